// Round 2
// baseline (677.718 us; speedup 1.0000x reference)
//
#include <hip/hip_runtime.h>
#include <hip/hip_bf16.h>

// Problem constants (match reference)
constexpr int B_    = 64;
constexpr int N_    = 1024;
constexpr int DEG_  = 32;
constexpr int CH_   = 128;            // IN_CH == HID == 128
constexpr int E_    = B_ * N_ * DEG_; // 2,097,152 edges
constexpr int NB_   = B_ * N_;        // 65,536 nodes
constexpr int K_    = N_ / 2;         // 512 kept per graph
constexpr int NK_   = B_ * K_;        // 32,768 pooled nodes

// ---------------------------------------------------------------------------
// scores[i] = tanh( dot(x[i], w_pool) / ||w_pool|| )   (wave per node)
// ---------------------------------------------------------------------------
__global__ __launch_bounds__(256) void scores_kernel(
    const float* __restrict__ x, const float* __restrict__ w_pool,
    float* __restrict__ scores, int n) {
  int wave = (blockIdx.x * blockDim.x + threadIdx.x) >> 6;
  int lane = threadIdx.x & 63;
  if (wave >= n) return;
  float w0 = w_pool[lane], w1 = w_pool[64 + lane];
  float a0 = x[(size_t)wave * CH_ + lane];
  float a1 = x[(size_t)wave * CH_ + 64 + lane];
  float dot = a0 * w0 + a1 * w1;
  float nrm = w0 * w0 + w1 * w1;
  #pragma unroll
  for (int m = 32; m > 0; m >>= 1) {
    dot += __shfl_xor(dot, m, 64);
    nrm += __shfl_xor(nrm, m, 64);
  }
  if (lane == 0) scores[wave] = tanhf(dot / sqrtf(nrm));
}

// ---------------------------------------------------------------------------
// Per-graph top-K via bitonic sort of 1024 (score,idx) keys.
// Descending by score, ties -> lower idx first (matches jax.lax.top_k).
// ---------------------------------------------------------------------------
__global__ __launch_bounds__(1024) void topk_kernel(
    const float* __restrict__ scores, int* __restrict__ perm,
    float* __restrict__ topv, int* __restrict__ new_idx) {
  __shared__ unsigned long long keys[N_];
  int b = blockIdx.x, t = threadIdx.x;
  float f = scores[b * N_ + t];
  unsigned u = __float_as_uint(f);
  u = (u & 0x80000000u) ? ~u : (u | 0x80000000u); // ascending-order uint key
  unsigned du = ~u;                               // descending score
  keys[t] = ((unsigned long long)du << 32) | (unsigned)t;
  __syncthreads();
  for (int size = 2; size <= N_; size <<= 1) {
    for (int stride = size >> 1; stride > 0; stride >>= 1) {
      int j = t ^ stride;
      if (j > t) {
        unsigned long long a = keys[t], bk = keys[j];
        bool asc = ((t & size) == 0);
        if ((a > bk) == asc) { keys[t] = bk; keys[j] = a; }
      }
      __syncthreads();
    }
  }
  int idx = (int)(keys[t] & 0xFFFFFFFFu);
  int g = b * N_ + idx;
  if (t < K_) {
    int r = b * K_ + t;
    perm[r] = g;
    topv[r] = scores[g];
    new_idx[g] = r;
  } else {
    new_idx[g] = -1;
  }
}

// ---------------------------------------------------------------------------
// One edge pass: histogram by dst (conv1) and by relabeled d2 (conv2)
// ---------------------------------------------------------------------------
__global__ void count_both_kernel(const int* __restrict__ src, const int* __restrict__ dst,
                                  const int* __restrict__ new_idx,
                                  int* __restrict__ counts1, int* __restrict__ counts2, int ne) {
  for (int e = blockIdx.x * blockDim.x + threadIdx.x; e < ne; e += gridDim.x * blockDim.x) {
    int s = src[e], d = dst[e];
    atomicAdd(&counts1[d], 1);
    int s2 = new_idx[s], d2 = new_idx[d];
    if (s2 >= 0 && d2 >= 0) atomicAdd(&counts2[d2], 1);
  }
}

// ---------------------------------------------------------------------------
// Two scans in one launch: block 0 -> counts1 (NB_), block 1 -> counts2 (NK_)
// ---------------------------------------------------------------------------
__global__ __launch_bounds__(1024) void scan_both_kernel(
    const int* __restrict__ counts1, int* __restrict__ offsets1, int* __restrict__ cursor1,
    const int* __restrict__ counts2, int* __restrict__ offsets2, int* __restrict__ cursor2) {
  __shared__ int part[1024];
  const int* counts; int* offsets; int* cursor; int n;
  if (blockIdx.x == 0) { counts = counts1; offsets = offsets1; cursor = cursor1; n = NB_; }
  else                 { counts = counts2; offsets = offsets2; cursor = cursor2; n = NK_; }
  int t = threadIdx.x;
  int chunk = n >> 10;
  int base = t * chunk;
  int sum = 0;
  for (int i = 0; i < chunk; ++i) sum += counts[base + i];
  part[t] = sum;
  __syncthreads();
  for (int d = 1; d < 1024; d <<= 1) {
    int v = (t >= d) ? part[t - d] : 0;
    __syncthreads();
    part[t] += v;
    __syncthreads();
  }
  int run = (t == 0) ? 0 : part[t - 1];
  for (int i = 0; i < chunk; ++i) {
    offsets[base + i] = run;
    cursor[base + i]  = run;
    run += counts[base + i];
  }
  if (t == 1023) offsets[n] = run;
}

// ---------------------------------------------------------------------------
// One edge pass: scatter src into csr1 (by dst) and s2 into csr2 (by d2)
// ---------------------------------------------------------------------------
__global__ void scatter_both_kernel(const int* __restrict__ src, const int* __restrict__ dst,
                                    const int* __restrict__ new_idx,
                                    int* __restrict__ cursor1, int* __restrict__ csr1,
                                    int* __restrict__ cursor2, int* __restrict__ csr2, int ne) {
  for (int e = blockIdx.x * blockDim.x + threadIdx.x; e < ne; e += gridDim.x * blockDim.x) {
    int s = src[e], d = dst[e];
    int pos = atomicAdd(&cursor1[d], 1);
    csr1[pos] = s;
    int s2 = new_idx[s], d2 = new_idx[d];
    if (s2 >= 0 && d2 >= 0) {
      int p2 = atomicAdd(&cursor2[d2], 1);
      csr2[p2] = s2;
    }
  }
}

// ---------------------------------------------------------------------------
// aggregate: out[i] = feat[i] + sum_{p in [offs[i],offs[i+1])} feat[csr_src[p]]
// wave per node, float2 per lane (128 ch), 4-neighbor unroll for MLP
// ---------------------------------------------------------------------------
__global__ __launch_bounds__(256) void aggregate_kernel(
    const float* __restrict__ feat, const int* __restrict__ offs,
    const int* __restrict__ srcs, float* __restrict__ out, int n) {
  int node = (blockIdx.x * blockDim.x + threadIdx.x) >> 6;
  int lane = threadIdx.x & 63;
  if (node >= n) return;
  const float2* f2 = reinterpret_cast<const float2*>(feat);
  float2 acc = f2[(size_t)node * 64 + lane];
  int s = offs[node], e = offs[node + 1];
  int p = s;
  for (; p + 4 <= e; p += 4) {
    int j0 = srcs[p], j1 = srcs[p + 1], j2 = srcs[p + 2], j3 = srcs[p + 3];
    float2 v0 = f2[(size_t)j0 * 64 + lane];
    float2 v1 = f2[(size_t)j1 * 64 + lane];
    float2 v2 = f2[(size_t)j2 * 64 + lane];
    float2 v3 = f2[(size_t)j3 * 64 + lane];
    acc.x += (v0.x + v1.x) + (v2.x + v3.x);
    acc.y += (v0.y + v1.y) + (v2.y + v3.y);
  }
  for (; p < e; ++p) {
    float2 v = f2[(size_t)srcs[p] * 64 + lane];
    acc.x += v.x; acc.y += v.y;
  }
  reinterpret_cast<float2*>(out)[(size_t)node * 64 + lane] = acc;
}

// ---------------------------------------------------------------------------
// Fused GEMM pair: out = relu( relu(in@Wa+ba) @ Wb + bb )
// Block: 256 threads, 64 rows. Intermediate tile stays in LDS.
// FINAL: instead of storing rows, block-reduce over rows and atomically
// accumulate the per-graph mean into out (d_out, pre-zeroed).
// ---------------------------------------------------------------------------
template <bool FINAL>
__global__ __launch_bounds__(256) void gemm_pair_kernel(
    const float* __restrict__ in,
    const float* __restrict__ Wa, const float* __restrict__ ba,
    const float* __restrict__ Wb, const float* __restrict__ bb,
    float* __restrict__ out) {
  __shared__ float As[64][CH_];
  int block_row = blockIdx.x * 64;
  const float4* in4 = reinterpret_cast<const float4*>(in);
  float4* As4 = reinterpret_cast<float4*>(&As[0][0]);
  #pragma unroll
  for (int i = 0; i < 8; ++i) {
    int idx = threadIdx.x + i * 256;               // 2048 float4 per tile
    As4[idx] = in4[(size_t)block_row * 32 + idx];
  }
  __syncthreads();
  int cg = threadIdx.x & 31;  // cols 4*cg..4*cg+3
  int rg = threadIdx.x >> 5;  // rows rg + 8*r

  float acc[8][4];
  // ---- GEMM 1: As @ Wa ----
  #pragma unroll
  for (int r = 0; r < 8; ++r)
    #pragma unroll
    for (int c = 0; c < 4; ++c) acc[r][c] = 0.f;
  for (int k = 0; k < CH_; k += 4) {
    float4 w0 = reinterpret_cast<const float4*>(Wa + (size_t)(k + 0) * CH_)[cg];
    float4 w1 = reinterpret_cast<const float4*>(Wa + (size_t)(k + 1) * CH_)[cg];
    float4 w2 = reinterpret_cast<const float4*>(Wa + (size_t)(k + 2) * CH_)[cg];
    float4 w3 = reinterpret_cast<const float4*>(Wa + (size_t)(k + 3) * CH_)[cg];
    #pragma unroll
    for (int r = 0; r < 8; ++r) {
      float4 a = *reinterpret_cast<const float4*>(&As[rg + r * 8][k]);
      acc[r][0] += a.x * w0.x + a.y * w1.x + a.z * w2.x + a.w * w3.x;
      acc[r][1] += a.x * w0.y + a.y * w1.y + a.z * w2.y + a.w * w3.y;
      acc[r][2] += a.x * w0.z + a.y * w1.z + a.z * w2.z + a.w * w3.z;
      acc[r][3] += a.x * w0.w + a.y * w1.w + a.z * w2.w + a.w * w3.w;
    }
  }
  float4 bav = reinterpret_cast<const float4*>(ba)[cg];
  __syncthreads();   // all GEMM1 reads of As done before overwrite
  #pragma unroll
  for (int r = 0; r < 8; ++r) {
    float4 o;
    o.x = fmaxf(acc[r][0] + bav.x, 0.f);
    o.y = fmaxf(acc[r][1] + bav.y, 0.f);
    o.z = fmaxf(acc[r][2] + bav.z, 0.f);
    o.w = fmaxf(acc[r][3] + bav.w, 0.f);
    *reinterpret_cast<float4*>(&As[rg + r * 8][4 * cg]) = o;
  }
  __syncthreads();

  // ---- GEMM 2: t @ Wb ----
  #pragma unroll
  for (int r = 0; r < 8; ++r)
    #pragma unroll
    for (int c = 0; c < 4; ++c) acc[r][c] = 0.f;
  for (int k = 0; k < CH_; k += 4) {
    float4 w0 = reinterpret_cast<const float4*>(Wb + (size_t)(k + 0) * CH_)[cg];
    float4 w1 = reinterpret_cast<const float4*>(Wb + (size_t)(k + 1) * CH_)[cg];
    float4 w2 = reinterpret_cast<const float4*>(Wb + (size_t)(k + 2) * CH_)[cg];
    float4 w3 = reinterpret_cast<const float4*>(Wb + (size_t)(k + 3) * CH_)[cg];
    #pragma unroll
    for (int r = 0; r < 8; ++r) {
      float4 a = *reinterpret_cast<const float4*>(&As[rg + r * 8][k]);
      acc[r][0] += a.x * w0.x + a.y * w1.x + a.z * w2.x + a.w * w3.x;
      acc[r][1] += a.x * w0.y + a.y * w1.y + a.z * w2.y + a.w * w3.y;
      acc[r][2] += a.x * w0.z + a.y * w1.z + a.z * w2.z + a.w * w3.z;
      acc[r][3] += a.x * w0.w + a.y * w1.w + a.z * w2.w + a.w * w3.w;
    }
  }
  float4 bbv = reinterpret_cast<const float4*>(bb)[cg];

  if (!FINAL) {
    #pragma unroll
    for (int r = 0; r < 8; ++r) {
      int row = block_row + rg + r * 8;
      float4 o;
      o.x = fmaxf(acc[r][0] + bbv.x, 0.f);
      o.y = fmaxf(acc[r][1] + bbv.y, 0.f);
      o.z = fmaxf(acc[r][2] + bbv.z, 0.f);
      o.w = fmaxf(acc[r][3] + bbv.w, 0.f);
      reinterpret_cast<float4*>(out + (size_t)row * CH_)[cg] = o;
    }
  } else {
    // relu + partial row-sum (this thread covers rows rg+8r)
    float4 part = make_float4(0.f, 0.f, 0.f, 0.f);
    #pragma unroll
    for (int r = 0; r < 8; ++r) {
      part.x += fmaxf(acc[r][0] + bbv.x, 0.f);
      part.y += fmaxf(acc[r][1] + bbv.y, 0.f);
      part.z += fmaxf(acc[r][2] + bbv.z, 0.f);
      part.w += fmaxf(acc[r][3] + bbv.w, 0.f);
    }
    __syncthreads();   // GEMM2 reads of As done; reuse LDS for reduction
    float4* red = reinterpret_cast<float4*>(&As[0][0]);  // red[rg*32+cg]
    red[rg * 32 + cg] = part;
    __syncthreads();
    if (rg == 0) {
      float4 tot = red[cg];
      #pragma unroll
      for (int q = 1; q < 8; ++q) {
        float4 t = red[q * 32 + cg];
        tot.x += t.x; tot.y += t.y; tot.z += t.z; tot.w += t.w;
      }
      int b = block_row / K_;
      const float scale = 1.0f / (float)K_;
      atomicAdd(&out[b * CH_ + 4 * cg + 0], tot.x * scale);
      atomicAdd(&out[b * CH_ + 4 * cg + 1], tot.y * scale);
      atomicAdd(&out[b * CH_ + 4 * cg + 2], tot.z * scale);
      atomicAdd(&out[b * CH_ + 4 * cg + 3], tot.w * scale);
    }
  }
}

// ---------------------------------------------------------------------------
// pooled[r] = out1[perm[r]] * topv[r]    (wave per row, float2 lanes)
// ---------------------------------------------------------------------------
__global__ __launch_bounds__(256) void pool_gather_kernel(
    const float* __restrict__ out1, const int* __restrict__ perm,
    const float* __restrict__ topv, float* __restrict__ pooled, int n) {
  int r = (blockIdx.x * blockDim.x + threadIdx.x) >> 6;
  int lane = threadIdx.x & 63;
  if (r >= n) return;
  int g = perm[r];
  float v = topv[r];
  float2 t = reinterpret_cast<const float2*>(out1)[(size_t)g * 64 + lane];
  t.x *= v; t.y *= v;
  reinterpret_cast<float2*>(pooled)[(size_t)r * 64 + lane] = t;
}

// ---------------------------------------------------------------------------
extern "C" void kernel_launch(void* const* d_in, const int* in_sizes, int n_in,
                              void* d_out, int out_size, void* d_ws, size_t ws_size,
                              hipStream_t stream) {
  const float* x      = (const float*)d_in[0];
  const int*   eidx   = (const int*)d_in[1];
  const int*   src    = eidx;         // row 0
  const int*   dst    = eidx + E_;    // row 1
  // d_in[2] = batch (unused; layout is contiguous per graph)
  const float* W1 = (const float*)d_in[3];
  const float* b1 = (const float*)d_in[4];
  const float* W2 = (const float*)d_in[5];
  const float* b2 = (const float*)d_in[6];
  const float* w_pool = (const float*)d_in[7];
  const float* W3 = (const float*)d_in[8];
  const float* b3 = (const float*)d_in[9];
  const float* W4 = (const float*)d_in[10];
  const float* b4 = (const float*)d_in[11];
  float* dout = (float*)d_out;

  // ---- workspace carve ----
  char* w = (char*)d_ws;
  auto carve = [&](size_t bytes) {
    char* p = w;
    w += (bytes + 255) & ~(size_t)255;
    return p;
  };
  float* bufA     = (float*)carve((size_t)NB_ * CH_ * 4);
  float* bufB     = (float*)carve((size_t)NB_ * CH_ * 4);
  int*   csr1     = (int*)  carve((size_t)E_ * 4);
  int*   csr2     = (int*)  carve((size_t)E_ * 4);
  int*   counts1  = (int*)  carve((size_t)(NB_ + NK_) * 4);  // counts2 adjacent
  int*   counts2  = counts1 + NB_;
  int*   offsets1 = (int*)  carve((size_t)(NB_ + 1) * 4);
  int*   cursor1  = (int*)  carve((size_t)NB_ * 4);
  int*   offsets2 = (int*)  carve((size_t)(NK_ + 1) * 4);
  int*   cursor2  = (int*)  carve((size_t)NK_ * 4);
  float* scores   = (float*)carve((size_t)NB_ * 4);
  int*   perm     = (int*)  carve((size_t)NK_ * 4);
  float* topv     = (float*)carve((size_t)NK_ * 4);
  int*   new_idx  = (int*)  carve((size_t)NB_ * 4);

  // zero histogram counters + output accumulator (ws/out are poisoned 0xAA)
  hipMemsetAsync(counts1, 0, (size_t)(NB_ + NK_) * 4, stream);
  hipMemsetAsync(dout, 0, (size_t)B_ * CH_ * 4, stream);

  // ---- pooling scores + per-graph top-K ----
  scores_kernel<<<NB_ / 4, 256, 0, stream>>>(x, w_pool, scores, NB_);
  topk_kernel<<<B_, 1024, 0, stream>>>(scores, perm, topv, new_idx);

  // ---- CSR build for both convs (2 edge passes total) ----
  count_both_kernel<<<2048, 256, 0, stream>>>(src, dst, new_idx, counts1, counts2, E_);
  scan_both_kernel<<<2, 1024, 0, stream>>>(counts1, offsets1, cursor1,
                                           counts2, offsets2, cursor2);
  scatter_both_kernel<<<2048, 256, 0, stream>>>(src, dst, new_idx,
                                                cursor1, csr1, cursor2, csr2, E_);

  // ---- conv1: h1 = x + sum(x[src]) ; out1 = relu(relu(h1@W1+b1)@W2+b2) ----
  aggregate_kernel<<<NB_ / 4, 256, 0, stream>>>(x, offsets1, csr1, bufA, NB_);
  gemm_pair_kernel<false><<<NB_ / 64, 256, 0, stream>>>(bufA, W1, b1, W2, b2, bufB);

  // ---- top-k gather + gate (bufB -> bufA) ----
  pool_gather_kernel<<<NK_ / 4, 256, 0, stream>>>(bufB, perm, topv, bufA, NK_);

  // ---- conv2 + fused global mean pool ----
  aggregate_kernel<<<NK_ / 4, 256, 0, stream>>>(bufA, offsets2, csr2, bufB, NK_);
  gemm_pair_kernel<true><<<NK_ / 64, 256, 0, stream>>>(bufB, W3, b3, W4, b4, dout);
}

// Round 4
// 543.511 us; speedup vs baseline: 1.2469x; 1.2469x over previous
//
#include <hip/hip_runtime.h>
#include <hip/hip_bf16.h>

// Problem constants (match reference)
constexpr int B_    = 64;
constexpr int N_    = 1024;
constexpr int DEG_  = 32;
constexpr int CH_   = 128;            // IN_CH == HID == 128
constexpr int E_    = B_ * N_ * DEG_; // 2,097,152 edges
constexpr int NB_   = B_ * N_;        // 65,536 nodes
constexpr int K_    = N_ / 2;         // 512 kept per graph
constexpr int NK_   = B_ * K_;        // 32,768 pooled nodes
constexpr int SCAN_BLOCKS_ = NB_ / 1024; // 64 blocks x 256 threads x int4

// ---------------------------------------------------------------------------
// scores[i] = tanh( dot(x[i], w_pool) / ||w_pool|| )   (wave per node)
// ---------------------------------------------------------------------------
__global__ __launch_bounds__(256) void scores_kernel(
    const float* __restrict__ x, const float* __restrict__ w_pool,
    float* __restrict__ scores, int n) {
  int wave = (blockIdx.x * blockDim.x + threadIdx.x) >> 6;
  int lane = threadIdx.x & 63;
  if (wave >= n) return;
  float w0 = w_pool[lane], w1 = w_pool[64 + lane];
  float a0 = x[(size_t)wave * CH_ + lane];
  float a1 = x[(size_t)wave * CH_ + 64 + lane];
  float dot = a0 * w0 + a1 * w1;
  float nrm = w0 * w0 + w1 * w1;
  #pragma unroll
  for (int m = 32; m > 0; m >>= 1) {
    dot += __shfl_xor(dot, m, 64);
    nrm += __shfl_xor(nrm, m, 64);
  }
  if (lane == 0) scores[wave] = tanhf(dot / sqrtf(nrm));
}

// ---------------------------------------------------------------------------
// Per-graph top-K via bitonic sort of 1024 (score,idx) keys.
// Descending by score, ties -> lower idx first (matches jax.lax.top_k).
// ---------------------------------------------------------------------------
__global__ __launch_bounds__(1024) void topk_kernel(
    const float* __restrict__ scores, int* __restrict__ perm,
    float* __restrict__ topv, int* __restrict__ new_idx) {
  __shared__ unsigned long long keys[N_];
  int b = blockIdx.x, t = threadIdx.x;
  float f = scores[b * N_ + t];
  unsigned u = __float_as_uint(f);
  u = (u & 0x80000000u) ? ~u : (u | 0x80000000u); // ascending-order uint key
  unsigned du = ~u;                               // descending score
  keys[t] = ((unsigned long long)du << 32) | (unsigned)t;
  __syncthreads();
  for (int size = 2; size <= N_; size <<= 1) {
    for (int stride = size >> 1; stride > 0; stride >>= 1) {
      int j = t ^ stride;
      if (j > t) {
        unsigned long long a = keys[t], bk = keys[j];
        bool asc = ((t & size) == 0);
        if ((a > bk) == asc) { keys[t] = bk; keys[j] = a; }
      }
      __syncthreads();
    }
  }
  int idx = (int)(keys[t] & 0xFFFFFFFFu);
  int g = b * N_ + idx;
  if (t < K_) {
    int r = b * K_ + t;
    perm[r] = g;
    topv[r] = scores[g];
    new_idx[g] = r;
  } else {
    new_idx[g] = -1;
  }
}

// ---------------------------------------------------------------------------
// Edge pass 1: histogram by dst (conv1 CSR only)
// ---------------------------------------------------------------------------
__global__ void count_kernel(const int* __restrict__ dst,
                             int* __restrict__ counts, int ne) {
  for (int e = blockIdx.x * blockDim.x + threadIdx.x; e < ne; e += gridDim.x * blockDim.x)
    atomicAdd(&counts[dst[e]], 1);
}

// ---------------------------------------------------------------------------
// Hierarchical exclusive scan over counts[NB_] (sum == E_, compile-time const)
// ---------------------------------------------------------------------------
__global__ __launch_bounds__(256) void scan_reduce_kernel(
    const int* __restrict__ counts, int* __restrict__ partials) {
  __shared__ int red[256];
  int b = blockIdx.x, t = threadIdx.x;
  const int4* c4 = reinterpret_cast<const int4*>(counts);
  int4 v = c4[b * 256 + t];
  red[t] = v.x + v.y + v.z + v.w;
  __syncthreads();
  #pragma unroll
  for (int d = 128; d > 0; d >>= 1) {
    if (t < d) red[t] += red[t + d];
    __syncthreads();
  }
  if (t == 0) partials[b] = red[0];
}

__global__ __launch_bounds__(64) void scan_partials_kernel(
    int* __restrict__ partials, int* __restrict__ offsets1) {
  __shared__ int p[64];
  int t = threadIdx.x;
  p[t] = partials[t];
  __syncthreads();
  #pragma unroll
  for (int d = 1; d < 64; d <<= 1) {
    int v = (t >= d) ? p[t - d] : 0;
    __syncthreads();
    p[t] += v;
    __syncthreads();
  }
  partials[t] = (t == 0) ? 0 : p[t - 1]; // exclusive
  if (t == 0) offsets1[NB_] = E_;
}

__global__ __launch_bounds__(256) void scan_write_kernel(
    const int* __restrict__ counts, const int* __restrict__ partials,
    int* __restrict__ offsets1, int* __restrict__ cursor1) {
  __shared__ int tsum[256];
  int b = blockIdx.x, t = threadIdx.x;
  const int4* c4 = reinterpret_cast<const int4*>(counts);
  int4 v = c4[b * 256 + t];
  tsum[t] = v.x + v.y + v.z + v.w;
  __syncthreads();
  #pragma unroll
  for (int d = 1; d < 256; d <<= 1) {
    int u = (t >= d) ? tsum[t - d] : 0;
    __syncthreads();
    tsum[t] += u;
    __syncthreads();
  }
  int tpref = partials[b] + ((t == 0) ? 0 : tsum[t - 1]); // exclusive prefix
  int idx = b * 256 + t;
  int4 o;
  o.x = tpref;
  o.y = o.x + v.x;
  o.z = o.y + v.y;
  o.w = o.z + v.z;
  reinterpret_cast<int4*>(offsets1)[idx] = o;
  reinterpret_cast<int4*>(cursor1)[idx]  = o;
}

// ---------------------------------------------------------------------------
// Edge pass 2: scatter src into csr1 buckets (by dst)
// ---------------------------------------------------------------------------
__global__ void scatter_kernel(const int* __restrict__ src, const int* __restrict__ dst,
                               int* __restrict__ cursor1, int* __restrict__ csr1, int ne) {
  for (int e = blockIdx.x * blockDim.x + threadIdx.x; e < ne; e += gridDim.x * blockDim.x) {
    int pos = atomicAdd(&cursor1[dst[e]], 1);
    csr1[pos] = src[e];
  }
}

// ---------------------------------------------------------------------------
// conv1 aggregate: out[i] = feat[i] + sum_{p in csr1 bucket i} feat[csr1[p]]
// wave per node, float2 per lane (128 ch), 4-neighbor unroll for MLP
// ---------------------------------------------------------------------------
__global__ __launch_bounds__(256) void aggregate_kernel(
    const float* __restrict__ feat, const int* __restrict__ offs,
    const int* __restrict__ srcs, float* __restrict__ out, int n) {
  int node = (blockIdx.x * blockDim.x + threadIdx.x) >> 6;
  int lane = threadIdx.x & 63;
  if (node >= n) return;
  const float2* f2 = reinterpret_cast<const float2*>(feat);
  float2 acc = f2[(size_t)node * 64 + lane];
  int s = offs[node], e = offs[node + 1];
  int p = s;
  for (; p + 4 <= e; p += 4) {
    int j0 = srcs[p], j1 = srcs[p + 1], j2 = srcs[p + 2], j3 = srcs[p + 3];
    float2 v0 = f2[(size_t)j0 * 64 + lane];
    float2 v1 = f2[(size_t)j1 * 64 + lane];
    float2 v2 = f2[(size_t)j2 * 64 + lane];
    float2 v3 = f2[(size_t)j3 * 64 + lane];
    acc.x += (v0.x + v1.x) + (v2.x + v3.x);
    acc.y += (v0.y + v1.y) + (v2.y + v3.y);
  }
  for (; p < e; ++p) {
    float2 v = f2[(size_t)srcs[p] * 64 + lane];
    acc.x += v.x; acc.y += v.y;
  }
  reinterpret_cast<float2*>(out)[(size_t)node * 64 + lane] = acc;
}

// ---------------------------------------------------------------------------
// conv2 aggregate WITHOUT csr2: for pooled row r (orig node g = perm[r]),
// walk csr1's bucket of g; neighbors j with new_idx[j] >= 0 survive.
//   out[r] = pooled[r] + sum_valid pooled[new_idx[j]]
// Neighbor index + predicate are wave-uniform (broadcast loads, no divergence).
// ---------------------------------------------------------------------------
__global__ __launch_bounds__(256) void aggregate2_kernel(
    const float* __restrict__ pooled, const int* __restrict__ perm,
    const int* __restrict__ offs1, const int* __restrict__ csr1,
    const int* __restrict__ new_idx, float* __restrict__ out) {
  int r = (blockIdx.x * blockDim.x + threadIdx.x) >> 6;
  int lane = threadIdx.x & 63;
  if (r >= NK_) return;
  const float2* f2 = reinterpret_cast<const float2*>(pooled);
  float2 acc = f2[(size_t)r * 64 + lane];
  int g = perm[r];
  int s = offs1[g], e = offs1[g + 1];
  int p = s;
  for (; p + 2 <= e; p += 2) {
    int r0 = new_idx[csr1[p]];
    int r1 = new_idx[csr1[p + 1]];
    if (r0 >= 0) {
      float2 v = f2[(size_t)r0 * 64 + lane];
      acc.x += v.x; acc.y += v.y;
    }
    if (r1 >= 0) {
      float2 v = f2[(size_t)r1 * 64 + lane];
      acc.x += v.x; acc.y += v.y;
    }
  }
  for (; p < e; ++p) {
    int r0 = new_idx[csr1[p]];
    if (r0 >= 0) {
      float2 v = f2[(size_t)r0 * 64 + lane];
      acc.x += v.x; acc.y += v.y;
    }
  }
  reinterpret_cast<float2*>(out)[(size_t)r * 64 + lane] = acc;
}

// ---------------------------------------------------------------------------
// Fused GEMM pair: out = relu( relu(in@Wa+ba) @ Wb + bb )
// Block: 256 threads, 64 rows. Intermediate tile stays in LDS.
// FINAL: block-reduce over rows, atomically accumulate per-graph mean.
// ---------------------------------------------------------------------------
template <bool FINAL>
__global__ __launch_bounds__(256) void gemm_pair_kernel(
    const float* __restrict__ in,
    const float* __restrict__ Wa, const float* __restrict__ ba,
    const float* __restrict__ Wb, const float* __restrict__ bb,
    float* __restrict__ out) {
  __shared__ float As[64][CH_];
  int block_row = blockIdx.x * 64;
  const float4* in4 = reinterpret_cast<const float4*>(in);
  float4* As4 = reinterpret_cast<float4*>(&As[0][0]);
  #pragma unroll
  for (int i = 0; i < 8; ++i) {
    int idx = threadIdx.x + i * 256;               // 2048 float4 per tile
    As4[idx] = in4[(size_t)block_row * 32 + idx];
  }
  __syncthreads();
  int cg = threadIdx.x & 31;  // cols 4*cg..4*cg+3
  int rg = threadIdx.x >> 5;  // rows rg + 8*r

  float acc[8][4];
  // ---- GEMM 1: As @ Wa ----
  #pragma unroll
  for (int r = 0; r < 8; ++r)
    #pragma unroll
    for (int c = 0; c < 4; ++c) acc[r][c] = 0.f;
  for (int k = 0; k < CH_; k += 4) {
    float4 w0 = reinterpret_cast<const float4*>(Wa + (size_t)(k + 0) * CH_)[cg];
    float4 w1 = reinterpret_cast<const float4*>(Wa + (size_t)(k + 1) * CH_)[cg];
    float4 w2 = reinterpret_cast<const float4*>(Wa + (size_t)(k + 2) * CH_)[cg];
    float4 w3 = reinterpret_cast<const float4*>(Wa + (size_t)(k + 3) * CH_)[cg];
    #pragma unroll
    for (int r = 0; r < 8; ++r) {
      float4 a = *reinterpret_cast<const float4*>(&As[rg + r * 8][k]);
      acc[r][0] += a.x * w0.x + a.y * w1.x + a.z * w2.x + a.w * w3.x;
      acc[r][1] += a.x * w0.y + a.y * w1.y + a.z * w2.y + a.w * w3.y;
      acc[r][2] += a.x * w0.z + a.y * w1.z + a.z * w2.z + a.w * w3.z;
      acc[r][3] += a.x * w0.w + a.y * w1.w + a.z * w2.w + a.w * w3.w;
    }
  }
  float4 bav = reinterpret_cast<const float4*>(ba)[cg];
  __syncthreads();   // all GEMM1 reads of As done before overwrite
  #pragma unroll
  for (int r = 0; r < 8; ++r) {
    float4 o;
    o.x = fmaxf(acc[r][0] + bav.x, 0.f);
    o.y = fmaxf(acc[r][1] + bav.y, 0.f);
    o.z = fmaxf(acc[r][2] + bav.z, 0.f);
    o.w = fmaxf(acc[r][3] + bav.w, 0.f);
    *reinterpret_cast<float4*>(&As[rg + r * 8][4 * cg]) = o;
  }
  __syncthreads();

  // ---- GEMM 2: t @ Wb ----
  #pragma unroll
  for (int r = 0; r < 8; ++r)
    #pragma unroll
    for (int c = 0; c < 4; ++c) acc[r][c] = 0.f;
  for (int k = 0; k < CH_; k += 4) {
    float4 w0 = reinterpret_cast<const float4*>(Wb + (size_t)(k + 0) * CH_)[cg];
    float4 w1 = reinterpret_cast<const float4*>(Wb + (size_t)(k + 1) * CH_)[cg];
    float4 w2 = reinterpret_cast<const float4*>(Wb + (size_t)(k + 2) * CH_)[cg];
    float4 w3 = reinterpret_cast<const float4*>(Wb + (size_t)(k + 3) * CH_)[cg];
    #pragma unroll
    for (int r = 0; r < 8; ++r) {
      float4 a = *reinterpret_cast<const float4*>(&As[rg + r * 8][k]);
      acc[r][0] += a.x * w0.x + a.y * w1.x + a.z * w2.x + a.w * w3.x;
      acc[r][1] += a.x * w0.y + a.y * w1.y + a.z * w2.y + a.w * w3.y;
      acc[r][2] += a.x * w0.z + a.y * w1.z + a.z * w2.z + a.w * w3.z;
      acc[r][3] += a.x * w0.w + a.y * w1.w + a.z * w2.w + a.w * w3.w;
    }
  }
  float4 bbv = reinterpret_cast<const float4*>(bb)[cg];

  if (!FINAL) {
    #pragma unroll
    for (int r = 0; r < 8; ++r) {
      int row = block_row + rg + r * 8;
      float4 o;
      o.x = fmaxf(acc[r][0] + bbv.x, 0.f);
      o.y = fmaxf(acc[r][1] + bbv.y, 0.f);
      o.z = fmaxf(acc[r][2] + bbv.z, 0.f);
      o.w = fmaxf(acc[r][3] + bbv.w, 0.f);
      reinterpret_cast<float4*>(out + (size_t)row * CH_)[cg] = o;
    }
  } else {
    // relu + partial row-sum (this thread covers rows rg+8r)
    float4 part = make_float4(0.f, 0.f, 0.f, 0.f);
    #pragma unroll
    for (int r = 0; r < 8; ++r) {
      part.x += fmaxf(acc[r][0] + bbv.x, 0.f);
      part.y += fmaxf(acc[r][1] + bbv.y, 0.f);
      part.z += fmaxf(acc[r][2] + bbv.z, 0.f);
      part.w += fmaxf(acc[r][3] + bbv.w, 0.f);
    }
    __syncthreads();   // GEMM2 reads of As done; reuse LDS for reduction
    float4* red = reinterpret_cast<float4*>(&As[0][0]);  // red[rg*32+cg]
    red[rg * 32 + cg] = part;
    __syncthreads();
    if (rg == 0) {
      float4 tot = red[cg];
      #pragma unroll
      for (int q = 1; q < 8; ++q) {
        float4 t = red[q * 32 + cg];
        tot.x += t.x; tot.y += t.y; tot.z += t.z; tot.w += t.w;
      }
      int b = block_row / K_;
      const float scale = 1.0f / (float)K_;
      atomicAdd(&out[b * CH_ + 4 * cg + 0], tot.x * scale);
      atomicAdd(&out[b * CH_ + 4 * cg + 1], tot.y * scale);
      atomicAdd(&out[b * CH_ + 4 * cg + 2], tot.z * scale);
      atomicAdd(&out[b * CH_ + 4 * cg + 3], tot.w * scale);
    }
  }
}

// ---------------------------------------------------------------------------
// pooled[r] = out1[perm[r]] * topv[r]    (wave per row, float2 lanes)
// ---------------------------------------------------------------------------
__global__ __launch_bounds__(256) void pool_gather_kernel(
    const float* __restrict__ out1, const int* __restrict__ perm,
    const float* __restrict__ topv, float* __restrict__ pooled, int n) {
  int r = (blockIdx.x * blockDim.x + threadIdx.x) >> 6;
  int lane = threadIdx.x & 63;
  if (r >= n) return;
  int g = perm[r];
  float v = topv[r];
  float2 t = reinterpret_cast<const float2*>(out1)[(size_t)g * 64 + lane];
  t.x *= v; t.y *= v;
  reinterpret_cast<float2*>(pooled)[(size_t)r * 64 + lane] = t;
}

// ---------------------------------------------------------------------------
extern "C" void kernel_launch(void* const* d_in, const int* in_sizes, int n_in,
                              void* d_out, int out_size, void* d_ws, size_t ws_size,
                              hipStream_t stream) {
  const float* x      = (const float*)d_in[0];
  const int*   eidx   = (const int*)d_in[1];
  const int*   src    = eidx;         // row 0
  const int*   dst    = eidx + E_;    // row 1
  // d_in[2] = batch (unused; layout is contiguous per graph)
  const float* W1 = (const float*)d_in[3];
  const float* b1 = (const float*)d_in[4];
  const float* W2 = (const float*)d_in[5];
  const float* b2 = (const float*)d_in[6];
  const float* w_pool = (const float*)d_in[7];
  const float* W3 = (const float*)d_in[8];
  const float* b3 = (const float*)d_in[9];
  const float* W4 = (const float*)d_in[10];
  const float* b4 = (const float*)d_in[11];
  float* dout = (float*)d_out;

  // ---- workspace carve ----
  char* w = (char*)d_ws;
  auto carve = [&](size_t bytes) {
    char* p = w;
    w += (bytes + 255) & ~(size_t)255;
    return p;
  };
  float* bufA     = (float*)carve((size_t)NB_ * CH_ * 4);
  float* bufB     = (float*)carve((size_t)NB_ * CH_ * 4);
  int*   csr1     = (int*)  carve((size_t)E_ * 4);
  int*   counts   = (int*)  carve((size_t)NB_ * 4);
  int*   partials = (int*)  carve((size_t)SCAN_BLOCKS_ * 4);
  int*   offsets1 = (int*)  carve((size_t)(NB_ + 4) * 4);
  int*   cursor1  = (int*)  carve((size_t)NB_ * 4);
  float* scores   = (float*)carve((size_t)NB_ * 4);
  int*   perm     = (int*)  carve((size_t)NK_ * 4);
  float* topv     = (float*)carve((size_t)NK_ * 4);
  int*   new_idx  = (int*)  carve((size_t)NB_ * 4);

  // zero histogram counters + output accumulator (ws/out are poisoned 0xAA)
  hipMemsetAsync(counts, 0, (size_t)NB_ * 4, stream);
  hipMemsetAsync(dout, 0, (size_t)B_ * CH_ * 4, stream);

  // ---- pooling scores + per-graph top-K ----
  scores_kernel<<<NB_ / 4, 256, 0, stream>>>(x, w_pool, scores, NB_);
  topk_kernel<<<B_, 1024, 0, stream>>>(scores, perm, topv, new_idx);

  // ---- conv1 CSR build (count -> 3-kernel scan -> scatter) ----
  count_kernel<<<2048, 256, 0, stream>>>(dst, counts, E_);
  scan_reduce_kernel<<<SCAN_BLOCKS_, 256, 0, stream>>>(counts, partials);
  scan_partials_kernel<<<1, 64, 0, stream>>>(partials, offsets1);
  scan_write_kernel<<<SCAN_BLOCKS_, 256, 0, stream>>>(counts, partials,
                                                      offsets1, cursor1);
  scatter_kernel<<<2048, 256, 0, stream>>>(src, dst, cursor1, csr1, E_);

  // ---- conv1: h1 = x + sum(x[src]) ; out1 = relu(relu(h1@W1+b1)@W2+b2) ----
  aggregate_kernel<<<NB_ / 4, 256, 0, stream>>>(x, offsets1, csr1, bufA, NB_);
  gemm_pair_kernel<false><<<NB_ / 64, 256, 0, stream>>>(bufA, W1, b1, W2, b2, bufB);

  // ---- top-k gather + gate (bufB -> bufA) ----
  pool_gather_kernel<<<NK_ / 4, 256, 0, stream>>>(bufB, perm, topv, bufA, NK_);

  // ---- conv2 aggregate via csr1 + new_idx filter (no csr2 build) ----
  aggregate2_kernel<<<NK_ / 4, 256, 0, stream>>>(bufA, perm, offsets1, csr1,
                                                 new_idx, bufB);

  // ---- conv2 MLP + fused global mean pool ----
  gemm_pair_kernel<true><<<NK_ / 64, 256, 0, stream>>>(bufB, W3, b3, W4, b4, dout);
}

// Round 5
// 518.824 us; speedup vs baseline: 1.3063x; 1.0476x over previous
//
#include <hip/hip_runtime.h>
#include <hip/hip_bf16.h>

// Problem constants (match reference)
constexpr int B_    = 64;
constexpr int N_    = 1024;
constexpr int DEG_  = 32;
constexpr int CH_   = 128;            // IN_CH == HID == 128
constexpr int E_    = B_ * N_ * DEG_; // 2,097,152 edges
constexpr int NB_   = B_ * N_;        // 65,536 nodes
constexpr int K_    = N_ / 2;         // 512 kept per graph
constexpr int NK_   = B_ * K_;        // 32,768 pooled nodes
constexpr int SCAN_BLOCKS_ = NB_ / 1024; // 64 blocks x 256 threads x int4

// XCD-aware block remap: MI355X round-robins blockIdx across 8 XCDs.
// work = (bid%8)*(nblocks/8) + bid/8 gives XCD c a CONTIGUOUS work range
// (= a contiguous run of graphs), so each XCD's gather working set fits its
// private 4 MB L2. Bijective when nblocks % 8 == 0 (16384 / 8192 here).
template <int NBLOCKS>
__device__ inline int xcd_work(int bid) {
  return (bid & 7) * (NBLOCKS / 8) + (bid >> 3);
}

// ---------------------------------------------------------------------------
// scores[i] = tanh( dot(x[i], w_pool) / ||w_pool|| )   (wave per node)
// ---------------------------------------------------------------------------
__global__ __launch_bounds__(256) void scores_kernel(
    const float* __restrict__ x, const float* __restrict__ w_pool,
    float* __restrict__ scores, int n) {
  int wave = (blockIdx.x * blockDim.x + threadIdx.x) >> 6;
  int lane = threadIdx.x & 63;
  if (wave >= n) return;
  float w0 = w_pool[lane], w1 = w_pool[64 + lane];
  float a0 = x[(size_t)wave * CH_ + lane];
  float a1 = x[(size_t)wave * CH_ + 64 + lane];
  float dot = a0 * w0 + a1 * w1;
  float nrm = w0 * w0 + w1 * w1;
  #pragma unroll
  for (int m = 32; m > 0; m >>= 1) {
    dot += __shfl_xor(dot, m, 64);
    nrm += __shfl_xor(nrm, m, 64);
  }
  if (lane == 0) scores[wave] = tanhf(dot / sqrtf(nrm));
}

// ---------------------------------------------------------------------------
// Per-graph top-K via bitonic sort of 1024 (score,idx) keys.
// Descending by score, ties -> lower idx first (matches jax.lax.top_k).
// ---------------------------------------------------------------------------
__global__ __launch_bounds__(1024) void topk_kernel(
    const float* __restrict__ scores, int* __restrict__ perm,
    float* __restrict__ topv, int* __restrict__ new_idx) {
  __shared__ unsigned long long keys[N_];
  int b = blockIdx.x, t = threadIdx.x;
  float f = scores[b * N_ + t];
  unsigned u = __float_as_uint(f);
  u = (u & 0x80000000u) ? ~u : (u | 0x80000000u); // ascending-order uint key
  unsigned du = ~u;                               // descending score
  keys[t] = ((unsigned long long)du << 32) | (unsigned)t;
  __syncthreads();
  for (int size = 2; size <= N_; size <<= 1) {
    for (int stride = size >> 1; stride > 0; stride >>= 1) {
      int j = t ^ stride;
      if (j > t) {
        unsigned long long a = keys[t], bk = keys[j];
        bool asc = ((t & size) == 0);
        if ((a > bk) == asc) { keys[t] = bk; keys[j] = a; }
      }
      __syncthreads();
    }
  }
  int idx = (int)(keys[t] & 0xFFFFFFFFu);
  int g = b * N_ + idx;
  if (t < K_) {
    int r = b * K_ + t;
    perm[r] = g;
    topv[r] = scores[g];
    new_idx[g] = r;
  } else {
    new_idx[g] = -1;
  }
}

// ---------------------------------------------------------------------------
// Edge pass 1: histogram by dst (conv1 CSR only)
// ---------------------------------------------------------------------------
__global__ void count_kernel(const int* __restrict__ dst,
                             int* __restrict__ counts, int ne) {
  for (int e = blockIdx.x * blockDim.x + threadIdx.x; e < ne; e += gridDim.x * blockDim.x)
    atomicAdd(&counts[dst[e]], 1);
}

// ---------------------------------------------------------------------------
// Hierarchical exclusive scan over counts[NB_] (sum == E_, compile-time const)
// ---------------------------------------------------------------------------
__global__ __launch_bounds__(256) void scan_reduce_kernel(
    const int* __restrict__ counts, int* __restrict__ partials) {
  __shared__ int red[256];
  int b = blockIdx.x, t = threadIdx.x;
  const int4* c4 = reinterpret_cast<const int4*>(counts);
  int4 v = c4[b * 256 + t];
  red[t] = v.x + v.y + v.z + v.w;
  __syncthreads();
  #pragma unroll
  for (int d = 128; d > 0; d >>= 1) {
    if (t < d) red[t] += red[t + d];
    __syncthreads();
  }
  if (t == 0) partials[b] = red[0];
}

__global__ __launch_bounds__(64) void scan_partials_kernel(
    int* __restrict__ partials, int* __restrict__ offsets1) {
  __shared__ int p[64];
  int t = threadIdx.x;
  p[t] = partials[t];
  __syncthreads();
  #pragma unroll
  for (int d = 1; d < 64; d <<= 1) {
    int v = (t >= d) ? p[t - d] : 0;
    __syncthreads();
    p[t] += v;
    __syncthreads();
  }
  partials[t] = (t == 0) ? 0 : p[t - 1]; // exclusive
  if (t == 0) offsets1[NB_] = E_;
}

__global__ __launch_bounds__(256) void scan_write_kernel(
    const int* __restrict__ counts, const int* __restrict__ partials,
    int* __restrict__ offsets1, int* __restrict__ cursor1) {
  __shared__ int tsum[256];
  int b = blockIdx.x, t = threadIdx.x;
  const int4* c4 = reinterpret_cast<const int4*>(counts);
  int4 v = c4[b * 256 + t];
  tsum[t] = v.x + v.y + v.z + v.w;
  __syncthreads();
  #pragma unroll
  for (int d = 1; d < 256; d <<= 1) {
    int u = (t >= d) ? tsum[t - d] : 0;
    __syncthreads();
    tsum[t] += u;
    __syncthreads();
  }
  int tpref = partials[b] + ((t == 0) ? 0 : tsum[t - 1]); // exclusive prefix
  int idx = b * 256 + t;
  int4 o;
  o.x = tpref;
  o.y = o.x + v.x;
  o.z = o.y + v.y;
  o.w = o.z + v.z;
  reinterpret_cast<int4*>(offsets1)[idx] = o;
  reinterpret_cast<int4*>(cursor1)[idx]  = o;
}

// ---------------------------------------------------------------------------
// Edge pass 2: scatter src into csr1 buckets (by dst)
// ---------------------------------------------------------------------------
__global__ void scatter_kernel(const int* __restrict__ src, const int* __restrict__ dst,
                               int* __restrict__ cursor1, int* __restrict__ csr1, int ne) {
  for (int e = blockIdx.x * blockDim.x + threadIdx.x; e < ne; e += gridDim.x * blockDim.x) {
    int pos = atomicAdd(&cursor1[dst[e]], 1);
    csr1[pos] = src[e];
  }
}

// ---------------------------------------------------------------------------
// conv1 aggregate: out[i] = feat[i] + sum_{p in csr1 bucket i} feat[csr1[p]]
// wave per node, float2 per lane (128 ch), 4-neighbor unroll for MLP.
// XCD-swizzled: each XCD works a contiguous run of 8 graphs (4 MB = its L2).
// ---------------------------------------------------------------------------
__global__ __launch_bounds__(256) void aggregate_kernel(
    const float* __restrict__ feat, const int* __restrict__ offs,
    const int* __restrict__ srcs, float* __restrict__ out) {
  int work = xcd_work<NB_ / 4>(blockIdx.x);
  int node = work * 4 + ((int)threadIdx.x >> 6);
  int lane = threadIdx.x & 63;
  const float2* f2 = reinterpret_cast<const float2*>(feat);
  float2 acc = f2[(size_t)node * 64 + lane];
  int s = offs[node], e = offs[node + 1];
  int p = s;
  for (; p + 4 <= e; p += 4) {
    int j0 = srcs[p], j1 = srcs[p + 1], j2 = srcs[p + 2], j3 = srcs[p + 3];
    float2 v0 = f2[(size_t)j0 * 64 + lane];
    float2 v1 = f2[(size_t)j1 * 64 + lane];
    float2 v2 = f2[(size_t)j2 * 64 + lane];
    float2 v3 = f2[(size_t)j3 * 64 + lane];
    acc.x += (v0.x + v1.x) + (v2.x + v3.x);
    acc.y += (v0.y + v1.y) + (v2.y + v3.y);
  }
  for (; p < e; ++p) {
    float2 v = f2[(size_t)srcs[p] * 64 + lane];
    acc.x += v.x; acc.y += v.y;
  }
  reinterpret_cast<float2*>(out)[(size_t)node * 64 + lane] = acc;
}

// ---------------------------------------------------------------------------
// conv2 aggregate WITHOUT csr2: for pooled row r (orig node g = perm[r]),
// walk csr1's bucket of g; neighbors j with new_idx[j] >= 0 survive.
//   out[r] = pooled[r] + sum_valid pooled[new_idx[j]]
// XCD-swizzled like aggregate_kernel (per-XCD slice of pooled = 2.1 MB).
// ---------------------------------------------------------------------------
__global__ __launch_bounds__(256) void aggregate2_kernel(
    const float* __restrict__ pooled, const int* __restrict__ perm,
    const int* __restrict__ offs1, const int* __restrict__ csr1,
    const int* __restrict__ new_idx, float* __restrict__ out) {
  int work = xcd_work<NK_ / 4>(blockIdx.x);
  int r = work * 4 + ((int)threadIdx.x >> 6);
  int lane = threadIdx.x & 63;
  const float2* f2 = reinterpret_cast<const float2*>(pooled);
  float2 acc = f2[(size_t)r * 64 + lane];
  int g = perm[r];
  int s = offs1[g], e = offs1[g + 1];
  int p = s;
  for (; p + 2 <= e; p += 2) {
    int r0 = new_idx[csr1[p]];
    int r1 = new_idx[csr1[p + 1]];
    if (r0 >= 0) {
      float2 v = f2[(size_t)r0 * 64 + lane];
      acc.x += v.x; acc.y += v.y;
    }
    if (r1 >= 0) {
      float2 v = f2[(size_t)r1 * 64 + lane];
      acc.x += v.x; acc.y += v.y;
    }
  }
  for (; p < e; ++p) {
    int r0 = new_idx[csr1[p]];
    if (r0 >= 0) {
      float2 v = f2[(size_t)r0 * 64 + lane];
      acc.x += v.x; acc.y += v.y;
    }
  }
  reinterpret_cast<float2*>(out)[(size_t)r * 64 + lane] = acc;
}

// ---------------------------------------------------------------------------
// Fused GEMM pair: out = relu( relu(in@Wa+ba) @ Wb + bb )
// Block: 256 threads, 64 rows. Intermediate tile stays in LDS.
// FINAL: block-reduce over rows, atomically accumulate per-graph mean.
// ---------------------------------------------------------------------------
template <bool FINAL>
__global__ __launch_bounds__(256) void gemm_pair_kernel(
    const float* __restrict__ in,
    const float* __restrict__ Wa, const float* __restrict__ ba,
    const float* __restrict__ Wb, const float* __restrict__ bb,
    float* __restrict__ out) {
  __shared__ float As[64][CH_];
  int block_row = blockIdx.x * 64;
  const float4* in4 = reinterpret_cast<const float4*>(in);
  float4* As4 = reinterpret_cast<float4*>(&As[0][0]);
  #pragma unroll
  for (int i = 0; i < 8; ++i) {
    int idx = threadIdx.x + i * 256;               // 2048 float4 per tile
    As4[idx] = in4[(size_t)block_row * 32 + idx];
  }
  __syncthreads();
  int cg = threadIdx.x & 31;  // cols 4*cg..4*cg+3
  int rg = threadIdx.x >> 5;  // rows rg + 8*r

  float acc[8][4];
  // ---- GEMM 1: As @ Wa ----
  #pragma unroll
  for (int r = 0; r < 8; ++r)
    #pragma unroll
    for (int c = 0; c < 4; ++c) acc[r][c] = 0.f;
  for (int k = 0; k < CH_; k += 4) {
    float4 w0 = reinterpret_cast<const float4*>(Wa + (size_t)(k + 0) * CH_)[cg];
    float4 w1 = reinterpret_cast<const float4*>(Wa + (size_t)(k + 1) * CH_)[cg];
    float4 w2 = reinterpret_cast<const float4*>(Wa + (size_t)(k + 2) * CH_)[cg];
    float4 w3 = reinterpret_cast<const float4*>(Wa + (size_t)(k + 3) * CH_)[cg];
    #pragma unroll
    for (int r = 0; r < 8; ++r) {
      float4 a = *reinterpret_cast<const float4*>(&As[rg + r * 8][k]);
      acc[r][0] += a.x * w0.x + a.y * w1.x + a.z * w2.x + a.w * w3.x;
      acc[r][1] += a.x * w0.y + a.y * w1.y + a.z * w2.y + a.w * w3.y;
      acc[r][2] += a.x * w0.z + a.y * w1.z + a.z * w2.z + a.w * w3.z;
      acc[r][3] += a.x * w0.w + a.y * w1.w + a.z * w2.w + a.w * w3.w;
    }
  }
  float4 bav = reinterpret_cast<const float4*>(ba)[cg];
  __syncthreads();   // all GEMM1 reads of As done before overwrite
  #pragma unroll
  for (int r = 0; r < 8; ++r) {
    float4 o;
    o.x = fmaxf(acc[r][0] + bav.x, 0.f);
    o.y = fmaxf(acc[r][1] + bav.y, 0.f);
    o.z = fmaxf(acc[r][2] + bav.z, 0.f);
    o.w = fmaxf(acc[r][3] + bav.w, 0.f);
    *reinterpret_cast<float4*>(&As[rg + r * 8][4 * cg]) = o;
  }
  __syncthreads();

  // ---- GEMM 2: t @ Wb ----
  #pragma unroll
  for (int r = 0; r < 8; ++r)
    #pragma unroll
    for (int c = 0; c < 4; ++c) acc[r][c] = 0.f;
  for (int k = 0; k < CH_; k += 4) {
    float4 w0 = reinterpret_cast<const float4*>(Wb + (size_t)(k + 0) * CH_)[cg];
    float4 w1 = reinterpret_cast<const float4*>(Wb + (size_t)(k + 1) * CH_)[cg];
    float4 w2 = reinterpret_cast<const float4*>(Wb + (size_t)(k + 2) * CH_)[cg];
    float4 w3 = reinterpret_cast<const float4*>(Wb + (size_t)(k + 3) * CH_)[cg];
    #pragma unroll
    for (int r = 0; r < 8; ++r) {
      float4 a = *reinterpret_cast<const float4*>(&As[rg + r * 8][k]);
      acc[r][0] += a.x * w0.x + a.y * w1.x + a.z * w2.x + a.w * w3.x;
      acc[r][1] += a.x * w0.y + a.y * w1.y + a.z * w2.y + a.w * w3.y;
      acc[r][2] += a.x * w0.z + a.y * w1.z + a.z * w2.z + a.w * w3.z;
      acc[r][3] += a.x * w0.w + a.y * w1.w + a.z * w2.w + a.w * w3.w;
    }
  }
  float4 bbv = reinterpret_cast<const float4*>(bb)[cg];

  if (!FINAL) {
    #pragma unroll
    for (int r = 0; r < 8; ++r) {
      int row = block_row + rg + r * 8;
      float4 o;
      o.x = fmaxf(acc[r][0] + bbv.x, 0.f);
      o.y = fmaxf(acc[r][1] + bbv.y, 0.f);
      o.z = fmaxf(acc[r][2] + bbv.z, 0.f);
      o.w = fmaxf(acc[r][3] + bbv.w, 0.f);
      reinterpret_cast<float4*>(out + (size_t)row * CH_)[cg] = o;
    }
  } else {
    // relu + partial row-sum (this thread covers rows rg+8r)
    float4 part = make_float4(0.f, 0.f, 0.f, 0.f);
    #pragma unroll
    for (int r = 0; r < 8; ++r) {
      part.x += fmaxf(acc[r][0] + bbv.x, 0.f);
      part.y += fmaxf(acc[r][1] + bbv.y, 0.f);
      part.z += fmaxf(acc[r][2] + bbv.z, 0.f);
      part.w += fmaxf(acc[r][3] + bbv.w, 0.f);
    }
    __syncthreads();   // GEMM2 reads of As done; reuse LDS for reduction
    float4* red = reinterpret_cast<float4*>(&As[0][0]);  // red[rg*32+cg]
    red[rg * 32 + cg] = part;
    __syncthreads();
    if (rg == 0) {
      float4 tot = red[cg];
      #pragma unroll
      for (int q = 1; q < 8; ++q) {
        float4 t = red[q * 32 + cg];
        tot.x += t.x; tot.y += t.y; tot.z += t.z; tot.w += t.w;
      }
      int b = block_row / K_;
      const float scale = 1.0f / (float)K_;
      atomicAdd(&out[b * CH_ + 4 * cg + 0], tot.x * scale);
      atomicAdd(&out[b * CH_ + 4 * cg + 1], tot.y * scale);
      atomicAdd(&out[b * CH_ + 4 * cg + 2], tot.z * scale);
      atomicAdd(&out[b * CH_ + 4 * cg + 3], tot.w * scale);
    }
  }
}

// ---------------------------------------------------------------------------
// pooled[r] = out1[perm[r]] * topv[r]  (wave per row, float2 lanes, XCD-swz)
// ---------------------------------------------------------------------------
__global__ __launch_bounds__(256) void pool_gather_kernel(
    const float* __restrict__ out1, const int* __restrict__ perm,
    const float* __restrict__ topv, float* __restrict__ pooled) {
  int work = xcd_work<NK_ / 4>(blockIdx.x);
  int r = work * 4 + ((int)threadIdx.x >> 6);
  int lane = threadIdx.x & 63;
  int g = perm[r];
  float v = topv[r];
  float2 t = reinterpret_cast<const float2*>(out1)[(size_t)g * 64 + lane];
  t.x *= v; t.y *= v;
  reinterpret_cast<float2*>(pooled)[(size_t)r * 64 + lane] = t;
}

// ---------------------------------------------------------------------------
extern "C" void kernel_launch(void* const* d_in, const int* in_sizes, int n_in,
                              void* d_out, int out_size, void* d_ws, size_t ws_size,
                              hipStream_t stream) {
  const float* x      = (const float*)d_in[0];
  const int*   eidx   = (const int*)d_in[1];
  const int*   src    = eidx;         // row 0
  const int*   dst    = eidx + E_;    // row 1
  // d_in[2] = batch (unused; layout is contiguous per graph)
  const float* W1 = (const float*)d_in[3];
  const float* b1 = (const float*)d_in[4];
  const float* W2 = (const float*)d_in[5];
  const float* b2 = (const float*)d_in[6];
  const float* w_pool = (const float*)d_in[7];
  const float* W3 = (const float*)d_in[8];
  const float* b3 = (const float*)d_in[9];
  const float* W4 = (const float*)d_in[10];
  const float* b4 = (const float*)d_in[11];
  float* dout = (float*)d_out;

  // ---- workspace carve ----
  char* w = (char*)d_ws;
  auto carve = [&](size_t bytes) {
    char* p = w;
    w += (bytes + 255) & ~(size_t)255;
    return p;
  };
  float* bufA     = (float*)carve((size_t)NB_ * CH_ * 4);
  float* bufB     = (float*)carve((size_t)NB_ * CH_ * 4);
  int*   csr1     = (int*)  carve((size_t)E_ * 4);
  int*   counts   = (int*)  carve((size_t)NB_ * 4);
  int*   partials = (int*)  carve((size_t)SCAN_BLOCKS_ * 4);
  int*   offsets1 = (int*)  carve((size_t)(NB_ + 4) * 4);
  int*   cursor1  = (int*)  carve((size_t)NB_ * 4);
  float* scores   = (float*)carve((size_t)NB_ * 4);
  int*   perm     = (int*)  carve((size_t)NK_ * 4);
  float* topv     = (float*)carve((size_t)NK_ * 4);
  int*   new_idx  = (int*)  carve((size_t)NB_ * 4);

  // zero histogram counters + output accumulator (ws/out are poisoned 0xAA)
  hipMemsetAsync(counts, 0, (size_t)NB_ * 4, stream);
  hipMemsetAsync(dout, 0, (size_t)B_ * CH_ * 4, stream);

  // ---- pooling scores + per-graph top-K ----
  scores_kernel<<<NB_ / 4, 256, 0, stream>>>(x, w_pool, scores, NB_);
  topk_kernel<<<B_, 1024, 0, stream>>>(scores, perm, topv, new_idx);

  // ---- conv1 CSR build (count -> 3-kernel scan -> scatter) ----
  count_kernel<<<2048, 256, 0, stream>>>(dst, counts, E_);
  scan_reduce_kernel<<<SCAN_BLOCKS_, 256, 0, stream>>>(counts, partials);
  scan_partials_kernel<<<1, 64, 0, stream>>>(partials, offsets1);
  scan_write_kernel<<<SCAN_BLOCKS_, 256, 0, stream>>>(counts, partials,
                                                      offsets1, cursor1);
  scatter_kernel<<<2048, 256, 0, stream>>>(src, dst, cursor1, csr1, E_);

  // ---- conv1: h1 = x + sum(x[src]) ; out1 = relu(relu(h1@W1+b1)@W2+b2) ----
  aggregate_kernel<<<NB_ / 4, 256, 0, stream>>>(x, offsets1, csr1, bufA);
  gemm_pair_kernel<false><<<NB_ / 64, 256, 0, stream>>>(bufA, W1, b1, W2, b2, bufB);

  // ---- top-k gather + gate (bufB -> bufA) ----
  pool_gather_kernel<<<NK_ / 4, 256, 0, stream>>>(bufB, perm, topv, bufA);

  // ---- conv2 aggregate via csr1 + new_idx filter (no csr2 build) ----
  aggregate2_kernel<<<NK_ / 4, 256, 0, stream>>>(bufA, perm, offsets1, csr1,
                                                 new_idx, bufB);

  // ---- conv2 MLP + fused global mean pool ----
  gemm_pair_kernel<true><<<NK_ / 64, 256, 0, stream>>>(bufB, W3, b3, W4, b4, dout);
}

// Round 8
// 416.040 us; speedup vs baseline: 1.6290x; 1.2471x over previous
//
#include <hip/hip_runtime.h>
#include <hip/hip_bf16.h>

// Problem constants (match reference)
constexpr int B_    = 64;
constexpr int N_    = 1024;
constexpr int DEG_  = 32;
constexpr int CH_   = 128;            // IN_CH == HID == 128
constexpr int E_    = B_ * N_ * DEG_; // 2,097,152 edges
constexpr int NB_   = B_ * N_;        // 65,536 nodes
constexpr int K_    = N_ / 2;         // 512 kept per graph
constexpr int NK_   = B_ * K_;        // 32,768 pooled nodes
constexpr int EPG_  = N_ * DEG_;      // 32,768 edges per graph (exact, by construction)

// XCD-aware block remap (bijective since nblocks % 8 == 0): each XCD gets a
// contiguous run of graphs so its gather working set fits its private 4MB L2.
template <int NBLOCKS>
__device__ inline int xcd_work(int bid) {
  return (bid & 7) * (NBLOCKS / 8) + (bid >> 3);
}

// ---------------------------------------------------------------------------
// scores[i] = tanh( dot(x[i], w_pool) / ||w_pool|| )   (wave per node)
// ---------------------------------------------------------------------------
__global__ __launch_bounds__(256) void scores_kernel(
    const float* __restrict__ x, const float* __restrict__ w_pool,
    float* __restrict__ scores, int n) {
  int wave = (blockIdx.x * blockDim.x + threadIdx.x) >> 6;
  int lane = threadIdx.x & 63;
  if (wave >= n) return;
  float w0 = w_pool[lane], w1 = w_pool[64 + lane];
  float a0 = x[(size_t)wave * CH_ + lane];
  float a1 = x[(size_t)wave * CH_ + 64 + lane];
  float dot = a0 * w0 + a1 * w1;
  float nrm = w0 * w0 + w1 * w1;
  #pragma unroll
  for (int m = 32; m > 0; m >>= 1) {
    dot += __shfl_xor(dot, m, 64);
    nrm += __shfl_xor(nrm, m, 64);
  }
  if (lane == 0) scores[wave] = tanhf(dot / sqrtf(nrm));
}

// ---------------------------------------------------------------------------
// Per-graph top-K via bitonic sort of 1024 (score,idx) keys.
// Descending by score, ties -> lower idx first (matches jax.lax.top_k).
// ---------------------------------------------------------------------------
__global__ __launch_bounds__(1024) void topk_kernel(
    const float* __restrict__ scores, int* __restrict__ perm,
    float* __restrict__ topv, int* __restrict__ new_idx) {
  __shared__ unsigned long long keys[N_];
  int b = blockIdx.x, t = threadIdx.x;
  float f = scores[b * N_ + t];
  unsigned u = __float_as_uint(f);
  u = (u & 0x80000000u) ? ~u : (u | 0x80000000u); // ascending-order uint key
  unsigned du = ~u;                               // descending score
  keys[t] = ((unsigned long long)du << 32) | (unsigned)t;
  __syncthreads();
  for (int size = 2; size <= N_; size <<= 1) {
    for (int stride = size >> 1; stride > 0; stride >>= 1) {
      int j = t ^ stride;
      if (j > t) {
        unsigned long long a = keys[t], bk = keys[j];
        bool asc = ((t & size) == 0);
        if ((a > bk) == asc) { keys[t] = bk; keys[j] = a; }
      }
      __syncthreads();
    }
  }
  int idx = (int)(keys[t] & 0xFFFFFFFFu);
  int g = b * N_ + idx;
  if (t < K_) {
    int r = b * K_ + t;
    perm[r] = g;
    topv[r] = scores[g];
    new_idx[g] = r;
  } else {
    new_idx[g] = -1;
  }
}

// ---------------------------------------------------------------------------
// Whole CSR build in ONE kernel: block b owns graph b (exactly EPG_ edges,
// dst ids in [b*N_,(b+1)*N_), CSR base = b*EPG_ statically).
// LDS histogram -> LDS shfl-scan -> LDS-cursor scatter. No global atomics.
// ---------------------------------------------------------------------------
__global__ __launch_bounds__(1024) void build_csr_kernel(
    const int* __restrict__ src, const int* __restrict__ dst,
    int* __restrict__ offsets1, int* __restrict__ csr1) {
  __shared__ int hist[N_];
  __shared__ int wsum[16];
  int b = blockIdx.x, t = threadIdx.x;
  hist[t] = 0;
  __syncthreads();
  const int ebase = b * EPG_;
  for (int k = t; k < EPG_; k += 1024)
    atomicAdd(&hist[dst[ebase + k] - b * N_], 1);
  __syncthreads();
  // exclusive scan of hist[1024]: intra-wave shfl scan + wave-partial scan
  int v = hist[t];
  int lane = t & 63;
  int incl = v;
  #pragma unroll
  for (int d = 1; d < 64; d <<= 1) {
    int n = __shfl_up(incl, d, 64);
    if (lane >= d) incl += n;
  }
  if (lane == 63) wsum[t >> 6] = incl;
  __syncthreads();
  if (t < 16) {
    int wv = wsum[t];
    int wincl = wv;
    #pragma unroll
    for (int d = 1; d < 16; d <<= 1) {
      int n = __shfl_up(wincl, d, 16);
      if ((t & 15) >= d) wincl += n;
    }
    wsum[t] = wincl - wv;   // exclusive wave prefix
  }
  __syncthreads();
  int excl = incl - v + wsum[t >> 6];
  offsets1[b * N_ + t] = ebase + excl;
  if (b == 0 && t == 0) offsets1[NB_] = E_;
  hist[t] = excl;           // becomes the local cursor
  __syncthreads();
  for (int k = t; k < EPG_; k += 1024) {
    int d = dst[ebase + k] - b * N_;
    int pos = atomicAdd(&hist[d], 1);
    csr1[ebase + pos] = src[ebase + k];
  }
}

// ---------------------------------------------------------------------------
// conv1 aggregate, PAIRED-ROW float4 gathers: lanes 0-31 read 16B of row j0,
// lanes 32-63 of row j1 -> 1KB per load instruction, half the instr count.
// Element stream = [node(self), neighbors...]; cross-half shfl_xor combine.
// ---------------------------------------------------------------------------
__global__ __launch_bounds__(256) void aggregate_kernel(
    const float* __restrict__ feat, const int* __restrict__ offs,
    const int* __restrict__ srcs, float* __restrict__ out) {
  int work = xcd_work<NB_ / 4>(blockIdx.x);
  int node = work * 4 + ((int)threadIdx.x >> 6);
  int lane = threadIdx.x & 63;
  int h = lane >> 5, li = lane & 31;
  const float4* f4 = reinterpret_cast<const float4*>(feat);
  int s = offs[node], e = offs[node + 1];
  int total = (e - s) + 1;          // +1 for self
  float4 acc = make_float4(0.f, 0.f, 0.f, 0.f);
  int i = 0;
  if (total >= 2) {                 // first pair = (self, srcs[s])
    int j = h ? srcs[s] : node;
    acc = f4[(size_t)j * 32 + li];
    i = 2;
  }
  // element k (k>=1) lives at srcs[s+k-1]; pairs (i,i+1),(i+2,i+3) in flight
  for (; i + 4 <= total; i += 4) {
    int ja = h ? srcs[s + i]     : srcs[s + i - 1];
    int jb = h ? srcs[s + i + 2] : srcs[s + i + 1];
    float4 va = f4[(size_t)ja * 32 + li];
    float4 vb = f4[(size_t)jb * 32 + li];
    acc.x += va.x + vb.x; acc.y += va.y + vb.y;
    acc.z += va.z + vb.z; acc.w += va.w + vb.w;
  }
  for (; i + 2 <= total; i += 2) {
    int j = h ? srcs[s + i] : srcs[s + i - 1];
    float4 v = f4[(size_t)j * 32 + li];
    acc.x += v.x; acc.y += v.y; acc.z += v.z; acc.w += v.w;
  }
  if (i < total) {                  // odd leftover -> half-wave load
    if (h == 0) {
      int j = (i == 0) ? node : srcs[s + i - 1];
      float4 v = f4[(size_t)j * 32 + li];
      acc.x += v.x; acc.y += v.y; acc.z += v.z; acc.w += v.w;
    }
  }
  acc.x += __shfl_xor(acc.x, 32, 64);
  acc.y += __shfl_xor(acc.y, 32, 64);
  acc.z += __shfl_xor(acc.z, 32, 64);
  acc.w += __shfl_xor(acc.w, 32, 64);
  if (h == 0)
    reinterpret_cast<float4*>(out)[(size_t)node * 32 + li] = acc;
}

// ---------------------------------------------------------------------------
// conv2 aggregate via csr1 + validity filter, paired-row float4 gathers.
// Valid elements stream through a wave-uniform pending/pair state machine
// (self row seeds the pipeline). No csr2 is ever built.
// ---------------------------------------------------------------------------
__global__ __launch_bounds__(256) void aggregate2_kernel(
    const float* __restrict__ pooled, const int* __restrict__ perm,
    const int* __restrict__ offs1, const int* __restrict__ csr1,
    const int* __restrict__ new_idx, float* __restrict__ out) {
  int work = xcd_work<NK_ / 4>(blockIdx.x);
  int r = work * 4 + ((int)threadIdx.x >> 6);
  int lane = threadIdx.x & 63;
  int h = lane >> 5, li = lane & 31;
  const float4* f4 = reinterpret_cast<const float4*>(pooled);
  int g = perm[r];
  int s = offs1[g], e = offs1[g + 1];
  float4 acc = make_float4(0.f, 0.f, 0.f, 0.f);
  int pend = r;                     // self row pending
  bool has = true;
  for (int p = s; p < e; ++p) {
    int rr = new_idx[csr1[p]];
    if (rr >= 0) {                  // wave-uniform predicate
      if (has) {                    // pair ready: (pend, rr)
        int j = h ? rr : pend;
        float4 v = f4[(size_t)j * 32 + li];
        acc.x += v.x; acc.y += v.y; acc.z += v.z; acc.w += v.w;
        has = false;
      } else {
        pend = rr; has = true;
      }
    }
  }
  if (has && h == 0) {              // odd leftover
    float4 v = f4[(size_t)pend * 32 + li];
    acc.x += v.x; acc.y += v.y; acc.z += v.z; acc.w += v.w;
  }
  acc.x += __shfl_xor(acc.x, 32, 64);
  acc.y += __shfl_xor(acc.y, 32, 64);
  acc.z += __shfl_xor(acc.z, 32, 64);
  acc.w += __shfl_xor(acc.w, 32, 64);
  if (h == 0)
    reinterpret_cast<float4*>(out)[(size_t)r * 32 + li] = acc;
}

// ---------------------------------------------------------------------------
// Fused GEMM pair: out = relu( relu(in@Wa+ba) @ Wb + bb )
// Block: 256 threads, 64 rows. Intermediate tile stays in LDS.
// FINAL: block-reduce over rows, atomically accumulate per-graph mean.
// ---------------------------------------------------------------------------
template <bool FINAL>
__global__ __launch_bounds__(256) void gemm_pair_kernel(
    const float* __restrict__ in,
    const float* __restrict__ Wa, const float* __restrict__ ba,
    const float* __restrict__ Wb, const float* __restrict__ bb,
    float* __restrict__ out) {
  __shared__ float As[64][CH_];
  int block_row = blockIdx.x * 64;
  const float4* in4 = reinterpret_cast<const float4*>(in);
  float4* As4 = reinterpret_cast<float4*>(&As[0][0]);
  #pragma unroll
  for (int i = 0; i < 8; ++i) {
    int idx = threadIdx.x + i * 256;               // 2048 float4 per tile
    As4[idx] = in4[(size_t)block_row * 32 + idx];
  }
  __syncthreads();
  int cg = threadIdx.x & 31;  // cols 4*cg..4*cg+3
  int rg = threadIdx.x >> 5;  // rows rg + 8*r

  float acc[8][4];
  // ---- GEMM 1: As @ Wa ----
  #pragma unroll
  for (int r = 0; r < 8; ++r)
    #pragma unroll
    for (int c = 0; c < 4; ++c) acc[r][c] = 0.f;
  for (int k = 0; k < CH_; k += 4) {
    float4 w0 = reinterpret_cast<const float4*>(Wa + (size_t)(k + 0) * CH_)[cg];
    float4 w1 = reinterpret_cast<const float4*>(Wa + (size_t)(k + 1) * CH_)[cg];
    float4 w2 = reinterpret_cast<const float4*>(Wa + (size_t)(k + 2) * CH_)[cg];
    float4 w3 = reinterpret_cast<const float4*>(Wa + (size_t)(k + 3) * CH_)[cg];
    #pragma unroll
    for (int r = 0; r < 8; ++r) {
      float4 a = *reinterpret_cast<const float4*>(&As[rg + r * 8][k]);
      acc[r][0] += a.x * w0.x + a.y * w1.x + a.z * w2.x + a.w * w3.x;
      acc[r][1] += a.x * w0.y + a.y * w1.y + a.z * w2.y + a.w * w3.y;
      acc[r][2] += a.x * w0.z + a.y * w1.z + a.z * w2.z + a.w * w3.z;
      acc[r][3] += a.x * w0.w + a.y * w1.w + a.z * w2.w + a.w * w3.w;
    }
  }
  float4 bav = reinterpret_cast<const float4*>(ba)[cg];
  __syncthreads();   // all GEMM1 reads of As done before overwrite
  #pragma unroll
  for (int r = 0; r < 8; ++r) {
    float4 o;
    o.x = fmaxf(acc[r][0] + bav.x, 0.f);
    o.y = fmaxf(acc[r][1] + bav.y, 0.f);
    o.z = fmaxf(acc[r][2] + bav.z, 0.f);
    o.w = fmaxf(acc[r][3] + bav.w, 0.f);
    *reinterpret_cast<float4*>(&As[rg + r * 8][4 * cg]) = o;
  }
  __syncthreads();

  // ---- GEMM 2: t @ Wb ----
  #pragma unroll
  for (int r = 0; r < 8; ++r)
    #pragma unroll
    for (int c = 0; c < 4; ++c) acc[r][c] = 0.f;
  for (int k = 0; k < CH_; k += 4) {
    float4 w0 = reinterpret_cast<const float4*>(Wb + (size_t)(k + 0) * CH_)[cg];
    float4 w1 = reinterpret_cast<const float4*>(Wb + (size_t)(k + 1) * CH_)[cg];
    float4 w2 = reinterpret_cast<const float4*>(Wb + (size_t)(k + 2) * CH_)[cg];
    float4 w3 = reinterpret_cast<const float4*>(Wb + (size_t)(k + 3) * CH_)[cg];
    #pragma unroll
    for (int r = 0; r < 8; ++r) {
      float4 a = *reinterpret_cast<const float4*>(&As[rg + r * 8][k]);
      acc[r][0] += a.x * w0.x + a.y * w1.x + a.z * w2.x + a.w * w3.x;
      acc[r][1] += a.x * w0.y + a.y * w1.y + a.z * w2.y + a.w * w3.y;
      acc[r][2] += a.x * w0.z + a.y * w1.z + a.z * w2.z + a.w * w3.z;
      acc[r][3] += a.x * w0.w + a.y * w1.w + a.z * w2.w + a.w * w3.w;
    }
  }
  float4 bbv = reinterpret_cast<const float4*>(bb)[cg];

  if (!FINAL) {
    #pragma unroll
    for (int r = 0; r < 8; ++r) {
      int row = block_row + rg + r * 8;
      float4 o;
      o.x = fmaxf(acc[r][0] + bbv.x, 0.f);
      o.y = fmaxf(acc[r][1] + bbv.y, 0.f);
      o.z = fmaxf(acc[r][2] + bbv.z, 0.f);
      o.w = fmaxf(acc[r][3] + bbv.w, 0.f);
      reinterpret_cast<float4*>(out + (size_t)row * CH_)[cg] = o;
    }
  } else {
    // relu + partial row-sum (this thread covers rows rg+8r)
    float4 part = make_float4(0.f, 0.f, 0.f, 0.f);
    #pragma unroll
    for (int r = 0; r < 8; ++r) {
      part.x += fmaxf(acc[r][0] + bbv.x, 0.f);
      part.y += fmaxf(acc[r][1] + bbv.y, 0.f);
      part.z += fmaxf(acc[r][2] + bbv.z, 0.f);
      part.w += fmaxf(acc[r][3] + bbv.w, 0.f);
    }
    __syncthreads();   // GEMM2 reads of As done; reuse LDS for reduction
    float4* red = reinterpret_cast<float4*>(&As[0][0]);  // red[rg*32+cg]
    red[rg * 32 + cg] = part;
    __syncthreads();
    if (rg == 0) {
      float4 tot = red[cg];
      #pragma unroll
      for (int q = 1; q < 8; ++q) {
        float4 t = red[q * 32 + cg];
        tot.x += t.x; tot.y += t.y; tot.z += t.z; tot.w += t.w;
      }
      int b = block_row / K_;
      const float scale = 1.0f / (float)K_;
      atomicAdd(&out[b * CH_ + 4 * cg + 0], tot.x * scale);
      atomicAdd(&out[b * CH_ + 4 * cg + 1], tot.y * scale);
      atomicAdd(&out[b * CH_ + 4 * cg + 2], tot.z * scale);
      atomicAdd(&out[b * CH_ + 4 * cg + 3], tot.w * scale);
    }
  }
}

// ---------------------------------------------------------------------------
// pooled[r] = out1[perm[r]] * topv[r]  (wave per row, float2 lanes, XCD-swz)
// ---------------------------------------------------------------------------
__global__ __launch_bounds__(256) void pool_gather_kernel(
    const float* __restrict__ out1, const int* __restrict__ perm,
    const float* __restrict__ topv, float* __restrict__ pooled) {
  int work = xcd_work<NK_ / 4>(blockIdx.x);
  int r = work * 4 + ((int)threadIdx.x >> 6);
  int lane = threadIdx.x & 63;
  int g = perm[r];
  float v = topv[r];
  float2 t = reinterpret_cast<const float2*>(out1)[(size_t)g * 64 + lane];
  t.x *= v; t.y *= v;
  reinterpret_cast<float2*>(pooled)[(size_t)r * 64 + lane] = t;
}

// ---------------------------------------------------------------------------
extern "C" void kernel_launch(void* const* d_in, const int* in_sizes, int n_in,
                              void* d_out, int out_size, void* d_ws, size_t ws_size,
                              hipStream_t stream) {
  const float* x      = (const float*)d_in[0];
  const int*   eidx   = (const int*)d_in[1];
  const int*   src    = eidx;         // row 0
  const int*   dst    = eidx + E_;    // row 1
  // d_in[2] = batch (unused; layout is contiguous per graph)
  const float* W1 = (const float*)d_in[3];
  const float* b1 = (const float*)d_in[4];
  const float* W2 = (const float*)d_in[5];
  const float* b2 = (const float*)d_in[6];
  const float* w_pool = (const float*)d_in[7];
  const float* W3 = (const float*)d_in[8];
  const float* b3 = (const float*)d_in[9];
  const float* W4 = (const float*)d_in[10];
  const float* b4 = (const float*)d_in[11];
  float* dout = (float*)d_out;

  // ---- workspace carve ----
  char* w = (char*)d_ws;
  auto carve = [&](size_t bytes) {
    char* p = w;
    w += (bytes + 255) & ~(size_t)255;
    return p;
  };
  float* bufA     = (float*)carve((size_t)NB_ * CH_ * 4);
  float* bufB     = (float*)carve((size_t)NB_ * CH_ * 4);
  int*   csr1     = (int*)  carve((size_t)E_ * 4);
  int*   offsets1 = (int*)  carve((size_t)(NB_ + 4) * 4);
  float* scores   = (float*)carve((size_t)NB_ * 4);
  int*   perm     = (int*)  carve((size_t)NK_ * 4);
  float* topv     = (float*)carve((size_t)NK_ * 4);
  int*   new_idx  = (int*)  carve((size_t)NB_ * 4);

  // zero output accumulator (out is poisoned 0xAA before every launch)
  hipMemsetAsync(dout, 0, (size_t)B_ * CH_ * 4, stream);

  // ---- pooling scores + per-graph top-K ----
  scores_kernel<<<NB_ / 4, 256, 0, stream>>>(x, w_pool, scores, NB_);
  topk_kernel<<<B_, 1024, 0, stream>>>(scores, perm, topv, new_idx);

  // ---- conv1 CSR build: one kernel, one block per graph, LDS hist+scan ----
  build_csr_kernel<<<B_, 1024, 0, stream>>>(src, dst, offsets1, csr1);

  // ---- conv1: h1 = x + sum(x[src]) ; out1 = relu(relu(h1@W1+b1)@W2+b2) ----
  aggregate_kernel<<<NB_ / 4, 256, 0, stream>>>(x, offsets1, csr1, bufA);
  gemm_pair_kernel<false><<<NB_ / 64, 256, 0, stream>>>(bufA, W1, b1, W2, b2, bufB);

  // ---- top-k gather + gate (bufB -> bufA) ----
  pool_gather_kernel<<<NK_ / 4, 256, 0, stream>>>(bufB, perm, topv, bufA);

  // ---- conv2 aggregate via csr1 + new_idx filter (no csr2 build) ----
  aggregate2_kernel<<<NK_ / 4, 256, 0, stream>>>(bufA, perm, offsets1, csr1,
                                                 new_idx, bufB);

  // ---- conv2 MLP + fused global mean pool ----
  gemm_pair_kernel<true><<<NK_ / 64, 256, 0, stream>>>(bufB, W3, b3, W4, b4, dout);
}

// Round 9
// 344.889 us; speedup vs baseline: 1.9650x; 1.2063x over previous
//
#include <hip/hip_runtime.h>
#include <hip/hip_bf16.h>

// Problem constants (match reference)
constexpr int B_    = 64;
constexpr int N_    = 1024;
constexpr int DEG_  = 32;
constexpr int CH_   = 128;            // IN_CH == HID == 128
constexpr int E_    = B_ * N_ * DEG_; // 2,097,152 edges
constexpr int NB_   = B_ * N_;        // 65,536 nodes
constexpr int K_    = N_ / 2;         // 512 kept per graph
constexpr int NK_   = B_ * K_;        // 32,768 pooled nodes
constexpr int EPG_  = N_ * DEG_;      // 32,768 edges per graph (exact, by construction)

typedef __attribute__((ext_vector_type(8))) short bf16x8;  // 8 bf16 = 4 VGPRs
typedef __attribute__((ext_vector_type(4))) float f32x4;

// XCD-aware block remap (bijective since nblocks % 8 == 0)
template <int NBLOCKS>
__device__ inline int xcd_work(int bid) {
  return (bid & 7) * (NBLOCKS / 8) + (bid >> 3);
}

// split f32 -> bf16 hi + bf16 lo (RNE), a ~= hi + lo with rel err ~2^-17
__device__ inline void split_bf16(float v, unsigned short& h, unsigned short& l) {
  unsigned u = __float_as_uint(v);
  unsigned hr = (u + 0x7FFFu + ((u >> 16) & 1u)) & 0xFFFF0000u;
  h = (unsigned short)(hr >> 16);
  float d = v - __uint_as_float(hr);
  unsigned ud = __float_as_uint(d);
  l = (unsigned short)((ud + 0x7FFFu + ((ud >> 16) & 1u)) >> 16);
}

// ---------------------------------------------------------------------------
// scores[i] = tanh( dot(x[i], w_pool) / ||w_pool|| )   (wave per node)
// ---------------------------------------------------------------------------
__global__ __launch_bounds__(256) void scores_kernel(
    const float* __restrict__ x, const float* __restrict__ w_pool,
    float* __restrict__ scores, int n) {
  int wave = (blockIdx.x * blockDim.x + threadIdx.x) >> 6;
  int lane = threadIdx.x & 63;
  if (wave >= n) return;
  float w0 = w_pool[lane], w1 = w_pool[64 + lane];
  float a0 = x[(size_t)wave * CH_ + lane];
  float a1 = x[(size_t)wave * CH_ + 64 + lane];
  float dot = a0 * w0 + a1 * w1;
  float nrm = w0 * w0 + w1 * w1;
  #pragma unroll
  for (int m = 32; m > 0; m >>= 1) {
    dot += __shfl_xor(dot, m, 64);
    nrm += __shfl_xor(nrm, m, 64);
  }
  if (lane == 0) scores[wave] = tanhf(dot / sqrtf(nrm));
}

// ---------------------------------------------------------------------------
// Per-graph top-K via bitonic sort of 1024 (score,idx) keys.
// ---------------------------------------------------------------------------
__global__ __launch_bounds__(1024) void topk_kernel(
    const float* __restrict__ scores, int* __restrict__ perm,
    float* __restrict__ topv, int* __restrict__ new_idx) {
  __shared__ unsigned long long keys[N_];
  int b = blockIdx.x, t = threadIdx.x;
  float f = scores[b * N_ + t];
  unsigned u = __float_as_uint(f);
  u = (u & 0x80000000u) ? ~u : (u | 0x80000000u);
  unsigned du = ~u;
  keys[t] = ((unsigned long long)du << 32) | (unsigned)t;
  __syncthreads();
  for (int size = 2; size <= N_; size <<= 1) {
    for (int stride = size >> 1; stride > 0; stride >>= 1) {
      int j = t ^ stride;
      if (j > t) {
        unsigned long long a = keys[t], bk = keys[j];
        bool asc = ((t & size) == 0);
        if ((a > bk) == asc) { keys[t] = bk; keys[j] = a; }
      }
      __syncthreads();
    }
  }
  int idx = (int)(keys[t] & 0xFFFFFFFFu);
  int g = b * N_ + idx;
  if (t < K_) {
    int r = b * K_ + t;
    perm[r] = g;
    topv[r] = scores[g];
    new_idx[g] = r;
  } else {
    new_idx[g] = -1;
  }
}

// ---------------------------------------------------------------------------
// CSR build in ONE kernel (block b owns graph b; LDS hist + scan + scatter)
// ---------------------------------------------------------------------------
__global__ __launch_bounds__(1024) void build_csr_kernel(
    const int* __restrict__ src, const int* __restrict__ dst,
    int* __restrict__ offsets1, int* __restrict__ csr1) {
  __shared__ int hist[N_];
  __shared__ int wsum[16];
  int b = blockIdx.x, t = threadIdx.x;
  hist[t] = 0;
  __syncthreads();
  const int ebase = b * EPG_;
  for (int k = t; k < EPG_; k += 1024)
    atomicAdd(&hist[dst[ebase + k] - b * N_], 1);
  __syncthreads();
  int v = hist[t];
  int lane = t & 63;
  int incl = v;
  #pragma unroll
  for (int d = 1; d < 64; d <<= 1) {
    int n = __shfl_up(incl, d, 64);
    if (lane >= d) incl += n;
  }
  if (lane == 63) wsum[t >> 6] = incl;
  __syncthreads();
  if (t < 16) {
    int wv = wsum[t];
    int wincl = wv;
    #pragma unroll
    for (int d = 1; d < 16; d <<= 1) {
      int n = __shfl_up(wincl, d, 16);
      if ((t & 15) >= d) wincl += n;
    }
    wsum[t] = wincl - wv;
  }
  __syncthreads();
  int excl = incl - v + wsum[t >> 6];
  offsets1[b * N_ + t] = ebase + excl;
  if (b == 0 && t == 0) offsets1[NB_] = E_;
  hist[t] = excl;
  __syncthreads();
  for (int k = t; k < EPG_; k += 1024) {
    int d = dst[ebase + k] - b * N_;
    int pos = atomicAdd(&hist[d], 1);
    csr1[ebase + pos] = src[ebase + k];
  }
}

// ---------------------------------------------------------------------------
// Pre-split + pre-fragment the 4 weight matrices into per-lane MFMA B-frag
// order: frag slot = (mat*32 + kb*8 + cg), lane l holds
// W[kb*32 + (l>>4)*8 + j][cg*16 + (l&15)], j=0..7, as bf16 hi/lo.
// 128 waves total (4 mats x 4 kb x 8 cg).
// ---------------------------------------------------------------------------
__global__ __launch_bounds__(256) void wfrag_kernel(
    const float* __restrict__ W1, const float* __restrict__ W2,
    const float* __restrict__ W3, const float* __restrict__ W4,
    unsigned short* __restrict__ whi, unsigned short* __restrict__ wlo) {
  int wid = (blockIdx.x * 256 + (int)threadIdx.x) >> 6;  // 0..127
  int l = threadIdx.x & 63;
  const float* Ws[4] = {W1, W2, W3, W4};
  int mat = wid >> 5, kb = (wid >> 3) & 3, cg = wid & 7;
  const float* W = Ws[mat];
  int col = cg * 16 + (l & 15);
  int kbase = kb * 32 + (l >> 4) * 8;
  bf16x8 hv, lv;
  #pragma unroll
  for (int j = 0; j < 8; ++j) {
    unsigned short h, lo;
    split_bf16(W[(size_t)(kbase + j) * CH_ + col], h, lo);
    hv[j] = (short)h; lv[j] = (short)lo;
  }
  size_t slot = ((size_t)mat * 32 + (size_t)(kb * 8 + cg)) * 64 + l;
  *reinterpret_cast<bf16x8*>(whi + slot * 8) = hv;
  *reinterpret_cast<bf16x8*>(wlo + slot * 8) = lv;
}

// ---------------------------------------------------------------------------
// conv1 aggregate (paired-row float4 gathers, XCD-swizzled) — unchanged
// ---------------------------------------------------------------------------
__global__ __launch_bounds__(256) void aggregate_kernel(
    const float* __restrict__ feat, const int* __restrict__ offs,
    const int* __restrict__ srcs, float* __restrict__ out) {
  int work = xcd_work<NB_ / 4>(blockIdx.x);
  int node = work * 4 + ((int)threadIdx.x >> 6);
  int lane = threadIdx.x & 63;
  int h = lane >> 5, li = lane & 31;
  const float4* f4 = reinterpret_cast<const float4*>(feat);
  int s = offs[node], e = offs[node + 1];
  int total = (e - s) + 1;
  float4 acc = make_float4(0.f, 0.f, 0.f, 0.f);
  int i = 0;
  if (total >= 2) {
    int j = h ? srcs[s] : node;
    acc = f4[(size_t)j * 32 + li];
    i = 2;
  }
  for (; i + 4 <= total; i += 4) {
    int ja = h ? srcs[s + i]     : srcs[s + i - 1];
    int jb = h ? srcs[s + i + 2] : srcs[s + i + 1];
    float4 va = f4[(size_t)ja * 32 + li];
    float4 vb = f4[(size_t)jb * 32 + li];
    acc.x += va.x + vb.x; acc.y += va.y + vb.y;
    acc.z += va.z + vb.z; acc.w += va.w + vb.w;
  }
  for (; i + 2 <= total; i += 2) {
    int j = h ? srcs[s + i] : srcs[s + i - 1];
    float4 v = f4[(size_t)j * 32 + li];
    acc.x += v.x; acc.y += v.y; acc.z += v.z; acc.w += v.w;
  }
  if (i < total) {
    if (h == 0) {
      int j = (i == 0) ? node : srcs[s + i - 1];
      float4 v = f4[(size_t)j * 32 + li];
      acc.x += v.x; acc.y += v.y; acc.z += v.z; acc.w += v.w;
    }
  }
  acc.x += __shfl_xor(acc.x, 32, 64);
  acc.y += __shfl_xor(acc.y, 32, 64);
  acc.z += __shfl_xor(acc.z, 32, 64);
  acc.w += __shfl_xor(acc.w, 32, 64);
  if (h == 0)
    reinterpret_cast<float4*>(out)[(size_t)node * 32 + li] = acc;
}

// ---------------------------------------------------------------------------
// conv2 aggregate via csr1 + validity filter — unchanged
// ---------------------------------------------------------------------------
__global__ __launch_bounds__(256) void aggregate2_kernel(
    const float* __restrict__ pooled, const int* __restrict__ perm,
    const int* __restrict__ offs1, const int* __restrict__ csr1,
    const int* __restrict__ new_idx, float* __restrict__ out) {
  int work = xcd_work<NK_ / 4>(blockIdx.x);
  int r = work * 4 + ((int)threadIdx.x >> 6);
  int lane = threadIdx.x & 63;
  int h = lane >> 5, li = lane & 31;
  const float4* f4 = reinterpret_cast<const float4*>(pooled);
  int g = perm[r];
  int s = offs1[g], e = offs1[g + 1];
  float4 acc = make_float4(0.f, 0.f, 0.f, 0.f);
  int pend = r;
  bool has = true;
  for (int p = s; p < e; ++p) {
    int rr = new_idx[csr1[p]];
    if (rr >= 0) {
      if (has) {
        int j = h ? rr : pend;
        float4 v = f4[(size_t)j * 32 + li];
        acc.x += v.x; acc.y += v.y; acc.z += v.z; acc.w += v.w;
        has = false;
      } else {
        pend = rr; has = true;
      }
    }
  }
  if (has && h == 0) {
    float4 v = f4[(size_t)pend * 32 + li];
    acc.x += v.x; acc.y += v.y; acc.z += v.z; acc.w += v.w;
  }
  acc.x += __shfl_xor(acc.x, 32, 64);
  acc.y += __shfl_xor(acc.y, 32, 64);
  acc.z += __shfl_xor(acc.z, 32, 64);
  acc.w += __shfl_xor(acc.w, 32, 64);
  if (h == 0)
    reinterpret_cast<float4*>(out)[(size_t)r * 32 + li] = acc;
}

// ---------------------------------------------------------------------------
// MFMA split-bf16 GEMM pair: out = relu( relu(in@Wa+ba) @ Wb + bb )
// a = a_hi + a_lo (bf16 each); a@W ~= ah@Wh + al@Wh + ah@Wl (3 MFMAs, f32 acc).
// 64 rows/block, 4 waves; wave w owns rows 16w..16w+15 (all 128 cols).
// A tiles live in LDS as bf16 hi/lo with XOR swizzle ((row&7)<<4 on byte addr)
// so ds_read_b128 A-frag loads are ~conflict-free (G4).
// t tile (after relu) re-split in-register and overwrites the same LDS.
// FINAL: fused mean-pool via LDS tree + 1 global atomic per col per block.
// ---------------------------------------------------------------------------
template <bool FINAL>
__global__ __launch_bounds__(256) void gemm_pair_mfma_kernel(
    const float* __restrict__ in,
    const unsigned short* __restrict__ wahi, const unsigned short* __restrict__ walo,
    const float* __restrict__ ba,
    const unsigned short* __restrict__ wbhi, const unsigned short* __restrict__ wblo,
    const float* __restrict__ bb,
    float* __restrict__ out) {
  __shared__ unsigned short Ahi[64 * CH_];  // 16 KB
  __shared__ unsigned short Alo[64 * CH_];  // 16 KB
  int tid = threadIdx.x;
  int w = tid >> 6, l = tid & 63;
  int block_row = blockIdx.x * 64;

  // ---- stage: f32 tile -> split bf16 hi/lo in LDS (swizzled) ----
  const float4* in4 = reinterpret_cast<const float4*>(in) + (size_t)block_row * 32;
  #pragma unroll
  for (int i = 0; i < 8; ++i) {
    int idx = tid + i * 256;            // float4 unit; 2048 total
    float4 v = in4[idx];
    int row = idx >> 5;
    int byte = row * 256 + (idx & 31) * 8;
    byte ^= (row & 7) << 4;
    unsigned short h0, l0, h1, l1, h2, l2, h3, l3;
    split_bf16(v.x, h0, l0); split_bf16(v.y, h1, l1);
    split_bf16(v.z, h2, l2); split_bf16(v.w, h3, l3);
    uint2 hp, lp;
    hp.x = (unsigned)h0 | ((unsigned)h1 << 16);
    hp.y = (unsigned)h2 | ((unsigned)h3 << 16);
    lp.x = (unsigned)l0 | ((unsigned)l1 << 16);
    lp.y = (unsigned)l2 | ((unsigned)l3 << 16);
    *reinterpret_cast<uint2*>(reinterpret_cast<char*>(Ahi) + byte) = hp;
    *reinterpret_cast<uint2*>(reinterpret_cast<char*>(Alo) + byte) = lp;
  }
  __syncthreads();

  // ---- A-frags for GEMM1 (8 x ds_read_b128) ----
  int arow = 16 * w + (l & 15);
  int kb_off = (l >> 4) * 16;           // byte offset of this lane's 8-k group
  bf16x8 a1h[4], a1l[4];
  #pragma unroll
  for (int kb = 0; kb < 4; ++kb) {
    int byte = arow * 256 + kb * 64 + kb_off;
    byte ^= (arow & 7) << 4;
    a1h[kb] = *reinterpret_cast<const bf16x8*>(reinterpret_cast<const char*>(Ahi) + byte);
    a1l[kb] = *reinterpret_cast<const bf16x8*>(reinterpret_cast<const char*>(Alo) + byte);
  }
  __syncthreads();                      // LDS free -> reuse for t tile

  int colbase = l & 15;
  int rowoff = (l >> 4) * 4;            // C/D: row=(l>>4)*4+reg, col=l&15 (m89)

  // ---- GEMM1 + bias + relu -> split t into LDS ----
  #pragma unroll 2
  for (int cg = 0; cg < 8; ++cg) {
    f32x4 acc1 = {0.f, 0.f, 0.f, 0.f};
    f32x4 acc2 = {0.f, 0.f, 0.f, 0.f};
    #pragma unroll
    for (int kb = 0; kb < 4; ++kb) {
      size_t slot = (size_t)(kb * 8 + cg) * 64 + l;
      bf16x8 bh = *reinterpret_cast<const bf16x8*>(wahi + slot * 8);
      bf16x8 bl = *reinterpret_cast<const bf16x8*>(walo + slot * 8);
      acc1 = __builtin_amdgcn_mfma_f32_16x16x32_bf16(a1h[kb], bh, acc1, 0, 0, 0);
      acc1 = __builtin_amdgcn_mfma_f32_16x16x32_bf16(a1h[kb], bl, acc1, 0, 0, 0);
      acc2 = __builtin_amdgcn_mfma_f32_16x16x32_bf16(a1l[kb], bh, acc2, 0, 0, 0);
    }
    int col = cg * 16 + colbase;
    float bv = ba[col];
    #pragma unroll
    for (int r = 0; r < 4; ++r) {
      float t = fmaxf(acc1[r] + acc2[r] + bv, 0.f);
      int trow = 16 * w + rowoff + r;
      int byte = (trow * 256 + col * 2) ^ ((trow & 7) << 4);
      unsigned short th, tl;
      split_bf16(t, th, tl);
      *reinterpret_cast<unsigned short*>(reinterpret_cast<char*>(Ahi) + byte) = th;
      *reinterpret_cast<unsigned short*>(reinterpret_cast<char*>(Alo) + byte) = tl;
    }
  }
  __syncthreads();

  // ---- A-frags for GEMM2 ----
  bf16x8 a2h[4], a2l[4];
  #pragma unroll
  for (int kb = 0; kb < 4; ++kb) {
    int byte = arow * 256 + kb * 64 + kb_off;
    byte ^= (arow & 7) << 4;
    a2h[kb] = *reinterpret_cast<const bf16x8*>(reinterpret_cast<const char*>(Ahi) + byte);
    a2l[kb] = *reinterpret_cast<const bf16x8*>(reinterpret_cast<const char*>(Alo) + byte);
  }
  if (FINAL) __syncthreads();           // all frag reads done before LDS reuse

  float* redf = reinterpret_cast<float*>(Ahi);  // FINAL: 16 x 128 partials (8 KB)

  // ---- GEMM2 (+bias [+relu]) -> store or fused mean-pool ----
  #pragma unroll 2
  for (int cg = 0; cg < 8; ++cg) {
    f32x4 acc1 = {0.f, 0.f, 0.f, 0.f};
    f32x4 acc2 = {0.f, 0.f, 0.f, 0.f};
    #pragma unroll
    for (int kb = 0; kb < 4; ++kb) {
      size_t slot = (size_t)(kb * 8 + cg) * 64 + l;
      bf16x8 bh = *reinterpret_cast<const bf16x8*>(wbhi + slot * 8);
      bf16x8 bl = *reinterpret_cast<const bf16x8*>(wblo + slot * 8);
      acc1 = __builtin_amdgcn_mfma_f32_16x16x32_bf16(a2h[kb], bh, acc1, 0, 0, 0);
      acc1 = __builtin_amdgcn_mfma_f32_16x16x32_bf16(a2h[kb], bl, acc1, 0, 0, 0);
      acc2 = __builtin_amdgcn_mfma_f32_16x16x32_bf16(a2l[kb], bh, acc2, 0, 0, 0);
    }
    int col = cg * 16 + colbase;
    float bv = bb[col];
    if (!FINAL) {
      #pragma unroll
      for (int r = 0; r < 4; ++r) {
        float v = fmaxf(acc1[r] + acc2[r] + bv, 0.f);
        out[(size_t)(block_row + 16 * w + rowoff + r) * CH_ + col] = v;
      }
    } else {
      float part = 0.f;
      #pragma unroll
      for (int r = 0; r < 4; ++r)
        part += fmaxf(acc1[r] + acc2[r] + bv, 0.f);
      redf[(w * 4 + (l >> 4)) * CH_ + col] = part;  // 16 row-groups x 128 cols
    }
  }

  if (FINAL) {
    __syncthreads();
    if (tid < CH_) {
      float tot = 0.f;
      #pragma unroll
      for (int s = 0; s < 16; ++s) tot += redf[s * CH_ + tid];
      int b = block_row / K_;
      atomicAdd(&out[b * CH_ + tid], tot * (1.0f / (float)K_));
    }
  }
}

// ---------------------------------------------------------------------------
// pooled[r] = out1[perm[r]] * topv[r]  (wave per row, float2 lanes, XCD-swz)
// ---------------------------------------------------------------------------
__global__ __launch_bounds__(256) void pool_gather_kernel(
    const float* __restrict__ out1, const int* __restrict__ perm,
    const float* __restrict__ topv, float* __restrict__ pooled) {
  int work = xcd_work<NK_ / 4>(blockIdx.x);
  int r = work * 4 + ((int)threadIdx.x >> 6);
  int lane = threadIdx.x & 63;
  int g = perm[r];
  float v = topv[r];
  float2 t = reinterpret_cast<const float2*>(out1)[(size_t)g * 64 + lane];
  t.x *= v; t.y *= v;
  reinterpret_cast<float2*>(pooled)[(size_t)r * 64 + lane] = t;
}

// ---------------------------------------------------------------------------
extern "C" void kernel_launch(void* const* d_in, const int* in_sizes, int n_in,
                              void* d_out, int out_size, void* d_ws, size_t ws_size,
                              hipStream_t stream) {
  const float* x      = (const float*)d_in[0];
  const int*   eidx   = (const int*)d_in[1];
  const int*   src    = eidx;         // row 0
  const int*   dst    = eidx + E_;    // row 1
  const float* W1 = (const float*)d_in[3];
  const float* b1 = (const float*)d_in[4];
  const float* W2 = (const float*)d_in[5];
  const float* b2 = (const float*)d_in[6];
  const float* w_pool = (const float*)d_in[7];
  const float* W3 = (const float*)d_in[8];
  const float* b3 = (const float*)d_in[9];
  const float* W4 = (const float*)d_in[10];
  const float* b4 = (const float*)d_in[11];
  float* dout = (float*)d_out;

  // ---- workspace carve ----
  char* w = (char*)d_ws;
  auto carve = [&](size_t bytes) {
    char* p = w;
    w += (bytes + 255) & ~(size_t)255;
    return p;
  };
  float*          bufA     = (float*)carve((size_t)NB_ * CH_ * 4);
  float*          bufB     = (float*)carve((size_t)NB_ * CH_ * 4);
  int*            csr1     = (int*)  carve((size_t)E_ * 4);
  int*            offsets1 = (int*)  carve((size_t)(NB_ + 4) * 4);
  float*          scores   = (float*)carve((size_t)NB_ * 4);
  int*            perm     = (int*)  carve((size_t)NK_ * 4);
  float*          topv     = (float*)carve((size_t)NK_ * 4);
  int*            new_idx  = (int*)  carve((size_t)NB_ * 4);
  unsigned short* whiB     = (unsigned short*)carve((size_t)4 * 16384 * 2);
  unsigned short* wloB     = (unsigned short*)carve((size_t)4 * 16384 * 2);
  // per-matrix frag offset: 16384 ushorts (32 slots x 64 lanes x 8)
  auto whi = [&](int m) { return whiB + (size_t)m * 16384; };
  auto wlo = [&](int m) { return wloB + (size_t)m * 16384; };

  // zero output accumulator (poisoned 0xAA before every launch)
  hipMemsetAsync(dout, 0, (size_t)B_ * CH_ * 4, stream);

  // ---- weight split + fragment pre-pass (once per call, ~5 us) ----
  wfrag_kernel<<<32, 256, 0, stream>>>(W1, W2, W3, W4, whiB, wloB);

  // ---- pooling scores + per-graph top-K ----
  scores_kernel<<<NB_ / 4, 256, 0, stream>>>(x, w_pool, scores, NB_);
  topk_kernel<<<B_, 1024, 0, stream>>>(scores, perm, topv, new_idx);

  // ---- conv1 CSR build ----
  build_csr_kernel<<<B_, 1024, 0, stream>>>(src, dst, offsets1, csr1);

  // ---- conv1: aggregate + MFMA MLP pair ----
  aggregate_kernel<<<NB_ / 4, 256, 0, stream>>>(x, offsets1, csr1, bufA);
  gemm_pair_mfma_kernel<false><<<NB_ / 64, 256, 0, stream>>>(
      bufA, whi(0), wlo(0), b1, whi(1), wlo(1), b2, bufB);

  // ---- top-k gather + gate (bufB -> bufA) ----
  pool_gather_kernel<<<NK_ / 4, 256, 0, stream>>>(bufB, perm, topv, bufA);

  // ---- conv2 aggregate via csr1 + new_idx filter ----
  aggregate2_kernel<<<NK_ / 4, 256, 0, stream>>>(bufA, perm, offsets1, csr1,
                                                 new_idx, bufB);

  // ---- conv2 MFMA MLP pair + fused global mean pool ----
  gemm_pair_mfma_kernel<true><<<NK_ / 64, 256, 0, stream>>>(
      bufB, whi(2), wlo(2), b3, whi(3), wlo(3), b4, dout);
}

// Round 10
// 315.709 us; speedup vs baseline: 2.1467x; 1.0924x over previous
//
#include <hip/hip_runtime.h>
#include <hip/hip_bf16.h>

// Problem constants (match reference)
constexpr int B_    = 64;
constexpr int N_    = 1024;
constexpr int DEG_  = 32;
constexpr int CH_   = 128;            // IN_CH == HID == 128
constexpr int E_    = B_ * N_ * DEG_; // 2,097,152 edges
constexpr int NB_   = B_ * N_;        // 65,536 nodes
constexpr int K_    = N_ / 2;         // 512 kept per graph
constexpr int NK_   = B_ * K_;        // 32,768 pooled nodes
constexpr int EPG_  = N_ * DEG_;      // 32,768 edges per graph
constexpr int CPB_  = 8;              // CSR-build chunks per graph
constexpr int CE_   = EPG_ / CPB_;    // 4096 edges per chunk

typedef __attribute__((ext_vector_type(8))) short bf16x8;  // 8 bf16 = 4 VGPRs
typedef __attribute__((ext_vector_type(4))) float f32x4;

// XCD-aware block remap (bijective since nblocks % 8 == 0)
template <int NBLOCKS>
__device__ inline int xcd_work(int bid) {
  return (bid & 7) * (NBLOCKS / 8) + (bid >> 3);
}

// split f32 -> bf16 hi + bf16 lo (RNE), a ~= hi + lo with rel err ~2^-17
__device__ inline void split_bf16(float v, unsigned short& h, unsigned short& l) {
  unsigned u = __float_as_uint(v);
  unsigned hr = (u + 0x7FFFu + ((u >> 16) & 1u)) & 0xFFFF0000u;
  h = (unsigned short)(hr >> 16);
  float d = v - __uint_as_float(hr);
  unsigned ud = __float_as_uint(d);
  l = (unsigned short)((ud + 0x7FFFu + ((ud >> 16) & 1u)) >> 16);
}

// ---------------------------------------------------------------------------
// scores[i] = tanh( dot(x[i], w_pool) / ||w_pool|| )   (wave per node)
// ---------------------------------------------------------------------------
__global__ __launch_bounds__(256) void scores_kernel(
    const float* __restrict__ x, const float* __restrict__ w_pool,
    float* __restrict__ scores, int n) {
  int wave = (blockIdx.x * blockDim.x + threadIdx.x) >> 6;
  int lane = threadIdx.x & 63;
  if (wave >= n) return;
  float w0 = w_pool[lane], w1 = w_pool[64 + lane];
  float a0 = x[(size_t)wave * CH_ + lane];
  float a1 = x[(size_t)wave * CH_ + 64 + lane];
  float dot = a0 * w0 + a1 * w1;
  float nrm = w0 * w0 + w1 * w1;
  #pragma unroll
  for (int m = 32; m > 0; m >>= 1) {
    dot += __shfl_xor(dot, m, 64);
    nrm += __shfl_xor(nrm, m, 64);
  }
  if (lane == 0) scores[wave] = tanhf(dot / sqrtf(nrm));
}

// ---------------------------------------------------------------------------
// Per-graph top-K via bitonic sort of 1024 (score,idx) keys.
// ---------------------------------------------------------------------------
__global__ __launch_bounds__(1024) void topk_kernel(
    const float* __restrict__ scores, int* __restrict__ perm,
    float* __restrict__ topv, int* __restrict__ new_idx) {
  __shared__ unsigned long long keys[N_];
  int b = blockIdx.x, t = threadIdx.x;
  float f = scores[b * N_ + t];
  unsigned u = __float_as_uint(f);
  u = (u & 0x80000000u) ? ~u : (u | 0x80000000u);
  unsigned du = ~u;
  keys[t] = ((unsigned long long)du << 32) | (unsigned)t;
  __syncthreads();
  for (int size = 2; size <= N_; size <<= 1) {
    for (int stride = size >> 1; stride > 0; stride >>= 1) {
      int j = t ^ stride;
      if (j > t) {
        unsigned long long a = keys[t], bk = keys[j];
        bool asc = ((t & size) == 0);
        if ((a > bk) == asc) { keys[t] = bk; keys[j] = a; }
      }
      __syncthreads();
    }
  }
  int idx = (int)(keys[t] & 0xFFFFFFFFu);
  int g = b * N_ + idx;
  if (t < K_) {
    int r = b * K_ + t;
    perm[r] = g;
    topv[r] = scores[g];
    new_idx[g] = r;
  } else {
    new_idx[g] = -1;
  }
}

// ---------------------------------------------------------------------------
// CSR build, chunked (8 chunks/graph = 512 blocks -> full-chip parallelism).
// A: per-chunk LDS histogram -> ph[chunk][1024]
// ---------------------------------------------------------------------------
__global__ __launch_bounds__(256) void csr_hist_kernel(
    const int* __restrict__ dst, int* __restrict__ ph) {
  __shared__ int hist[N_];
  int c = blockIdx.x, t = threadIdx.x;
  int b = c >> 3;
  reinterpret_cast<int4*>(hist)[t] = make_int4(0, 0, 0, 0);
  __syncthreads();
  const int ebase = b * EPG_ + (c & 7) * CE_;
  const int4* d4 = reinterpret_cast<const int4*>(dst + ebase);
  #pragma unroll
  for (int i = 0; i < 4; ++i) {
    int4 d = d4[t + i * 256];
    atomicAdd(&hist[d.x - b * N_], 1);
    atomicAdd(&hist[d.y - b * N_], 1);
    atomicAdd(&hist[d.z - b * N_], 1);
    atomicAdd(&hist[d.w - b * N_], 1);
  }
  __syncthreads();
  int4* out4 = reinterpret_cast<int4*>(ph + (size_t)c * N_);
  out4[t] = reinterpret_cast<const int4*>(hist)[t];
}

// ---------------------------------------------------------------------------
// B: per-graph scan. Thread n: chunk-prefix of ph[b*8+q][n], block shfl-scan
// of node totals -> offsets1; overwrite ph with ABSOLUTE chunk-start cursors.
// All ph accesses coalesced (consecutive n).
// ---------------------------------------------------------------------------
__global__ __launch_bounds__(1024) void csr_scan_kernel(
    int* __restrict__ ph, int* __restrict__ offsets1) {
  __shared__ int wsum[16];
  int b = blockIdx.x, n = threadIdx.x;
  int c[CPB_], pre[CPB_];
  int tot = 0;
  #pragma unroll
  for (int q = 0; q < CPB_; ++q) {
    c[q] = ph[(size_t)(b * CPB_ + q) * N_ + n];
    pre[q] = tot;
    tot += c[q];
  }
  int lane = n & 63;
  int incl = tot;
  #pragma unroll
  for (int d = 1; d < 64; d <<= 1) {
    int v = __shfl_up(incl, d, 64);
    if (lane >= d) incl += v;
  }
  if (lane == 63) wsum[n >> 6] = incl;
  __syncthreads();
  if (n < 16) {
    int wv = wsum[n];
    int wincl = wv;
    #pragma unroll
    for (int d = 1; d < 16; d <<= 1) {
      int v = __shfl_up(wincl, d, 16);
      if ((n & 15) >= d) wincl += v;
    }
    wsum[n] = wincl - wv;
  }
  __syncthreads();
  int excl = incl - tot + wsum[n >> 6];
  int base = b * EPG_ + excl;
  offsets1[b * N_ + n] = base;
  if (b == 0 && n == 0) offsets1[NB_] = E_;
  #pragma unroll
  for (int q = 0; q < CPB_; ++q)
    ph[(size_t)(b * CPB_ + q) * N_ + n] = base + pre[q];
}

// ---------------------------------------------------------------------------
// C: per-chunk scatter with LDS cursors. Also writes the TRANSLATED id
// csr1t[pos] = new_idx[src] so conv2 needs no per-edge lookup.
// ---------------------------------------------------------------------------
__global__ __launch_bounds__(256) void csr_scatter_kernel(
    const int* __restrict__ src, const int* __restrict__ dst,
    const int* __restrict__ ph, const int* __restrict__ new_idx,
    int* __restrict__ csr1, int* __restrict__ csr1t) {
  __shared__ int cursor[N_];
  int c = blockIdx.x, t = threadIdx.x;
  int b = c >> 3;
  reinterpret_cast<int4*>(cursor)[t] =
      reinterpret_cast<const int4*>(ph + (size_t)c * N_)[t];
  __syncthreads();
  const int ebase = b * EPG_ + (c & 7) * CE_;
  const int4* s4 = reinterpret_cast<const int4*>(src + ebase);
  const int4* d4 = reinterpret_cast<const int4*>(dst + ebase);
  #pragma unroll
  for (int i = 0; i < 4; ++i) {
    int4 s = s4[t + i * 256];
    int4 d = d4[t + i * 256];
    int p0 = atomicAdd(&cursor[d.x - b * N_], 1);
    csr1[p0] = s.x; csr1t[p0] = new_idx[s.x];
    int p1 = atomicAdd(&cursor[d.y - b * N_], 1);
    csr1[p1] = s.y; csr1t[p1] = new_idx[s.y];
    int p2 = atomicAdd(&cursor[d.z - b * N_], 1);
    csr1[p2] = s.z; csr1t[p2] = new_idx[s.z];
    int p3 = atomicAdd(&cursor[d.w - b * N_], 1);
    csr1[p3] = s.w; csr1t[p3] = new_idx[s.w];
  }
}

// ---------------------------------------------------------------------------
// Pre-split + pre-fragment the 4 weight matrices into per-lane MFMA B-frag
// order (see round-9 notes). 128 waves total.
// ---------------------------------------------------------------------------
__global__ __launch_bounds__(256) void wfrag_kernel(
    const float* __restrict__ W1, const float* __restrict__ W2,
    const float* __restrict__ W3, const float* __restrict__ W4,
    unsigned short* __restrict__ whi, unsigned short* __restrict__ wlo) {
  int wid = (blockIdx.x * 256 + (int)threadIdx.x) >> 6;  // 0..127
  int l = threadIdx.x & 63;
  const float* Ws[4] = {W1, W2, W3, W4};
  int mat = wid >> 5, kb = (wid >> 3) & 3, cg = wid & 7;
  const float* W = Ws[mat];
  int col = cg * 16 + (l & 15);
  int kbase = kb * 32 + (l >> 4) * 8;
  bf16x8 hv, lv;
  #pragma unroll
  for (int j = 0; j < 8; ++j) {
    unsigned short h, lo;
    split_bf16(W[(size_t)(kbase + j) * CH_ + col], h, lo);
    hv[j] = (short)h; lv[j] = (short)lo;
  }
  size_t slot = ((size_t)mat * 32 + (size_t)(kb * 8 + cg)) * 64 + l;
  *reinterpret_cast<bf16x8*>(whi + slot * 8) = hv;
  *reinterpret_cast<bf16x8*>(wlo + slot * 8) = lv;
}

// ---------------------------------------------------------------------------
// conv1 aggregate (paired-row float4 gathers, XCD-swizzled) — unchanged
// ---------------------------------------------------------------------------
__global__ __launch_bounds__(256) void aggregate_kernel(
    const float* __restrict__ feat, const int* __restrict__ offs,
    const int* __restrict__ srcs, float* __restrict__ out) {
  int work = xcd_work<NB_ / 4>(blockIdx.x);
  int node = work * 4 + ((int)threadIdx.x >> 6);
  int lane = threadIdx.x & 63;
  int h = lane >> 5, li = lane & 31;
  const float4* f4 = reinterpret_cast<const float4*>(feat);
  int s = offs[node], e = offs[node + 1];
  int total = (e - s) + 1;
  float4 acc = make_float4(0.f, 0.f, 0.f, 0.f);
  int i = 0;
  if (total >= 2) {
    int j = h ? srcs[s] : node;
    acc = f4[(size_t)j * 32 + li];
    i = 2;
  }
  for (; i + 4 <= total; i += 4) {
    int ja = h ? srcs[s + i]     : srcs[s + i - 1];
    int jb = h ? srcs[s + i + 2] : srcs[s + i + 1];
    float4 va = f4[(size_t)ja * 32 + li];
    float4 vb = f4[(size_t)jb * 32 + li];
    acc.x += va.x + vb.x; acc.y += va.y + vb.y;
    acc.z += va.z + vb.z; acc.w += va.w + vb.w;
  }
  for (; i + 2 <= total; i += 2) {
    int j = h ? srcs[s + i] : srcs[s + i - 1];
    float4 v = f4[(size_t)j * 32 + li];
    acc.x += v.x; acc.y += v.y; acc.z += v.z; acc.w += v.w;
  }
  if (i < total) {
    if (h == 0) {
      int j = (i == 0) ? node : srcs[s + i - 1];
      float4 v = f4[(size_t)j * 32 + li];
      acc.x += v.x; acc.y += v.y; acc.z += v.z; acc.w += v.w;
    }
  }
  acc.x += __shfl_xor(acc.x, 32, 64);
  acc.y += __shfl_xor(acc.y, 32, 64);
  acc.z += __shfl_xor(acc.z, 32, 64);
  acc.w += __shfl_xor(acc.w, 32, 64);
  if (h == 0)
    reinterpret_cast<float4*>(out)[(size_t)node * 32 + li] = acc;
}

// ---------------------------------------------------------------------------
// conv2 aggregate from PRE-TRANSLATED csr1t: 4-wide unrolled predicated
// float2 loads (4 independent gather chains, wave-uniform branches).
// ---------------------------------------------------------------------------
__global__ __launch_bounds__(256) void aggregate2_kernel(
    const float* __restrict__ pooled, const int* __restrict__ perm,
    const int* __restrict__ offs1, const int* __restrict__ csr1t,
    float* __restrict__ out) {
  int work = xcd_work<NK_ / 4>(blockIdx.x);
  int r = work * 4 + ((int)threadIdx.x >> 6);
  int lane = threadIdx.x & 63;
  const float2* f2 = reinterpret_cast<const float2*>(pooled);
  int g = perm[r];
  int s = offs1[g], e = offs1[g + 1];
  float2 acc = f2[(size_t)r * 64 + lane];
  int p = s;
  for (; p + 4 <= e; p += 4) {
    int r0 = csr1t[p], r1 = csr1t[p + 1], r2 = csr1t[p + 2], r3 = csr1t[p + 3];
    if (r0 >= 0) { float2 v = f2[(size_t)r0 * 64 + lane]; acc.x += v.x; acc.y += v.y; }
    if (r1 >= 0) { float2 v = f2[(size_t)r1 * 64 + lane]; acc.x += v.x; acc.y += v.y; }
    if (r2 >= 0) { float2 v = f2[(size_t)r2 * 64 + lane]; acc.x += v.x; acc.y += v.y; }
    if (r3 >= 0) { float2 v = f2[(size_t)r3 * 64 + lane]; acc.x += v.x; acc.y += v.y; }
  }
  for (; p < e; ++p) {
    int r0 = csr1t[p];
    if (r0 >= 0) { float2 v = f2[(size_t)r0 * 64 + lane]; acc.x += v.x; acc.y += v.y; }
  }
  reinterpret_cast<float2*>(out)[(size_t)r * 64 + lane] = acc;
}

// ---------------------------------------------------------------------------
// MFMA split-bf16 GEMM pair (unchanged from round 9; verified absmax 0.0625)
// ---------------------------------------------------------------------------
template <bool FINAL>
__global__ __launch_bounds__(256) void gemm_pair_mfma_kernel(
    const float* __restrict__ in,
    const unsigned short* __restrict__ wahi, const unsigned short* __restrict__ walo,
    const float* __restrict__ ba,
    const unsigned short* __restrict__ wbhi, const unsigned short* __restrict__ wblo,
    const float* __restrict__ bb,
    float* __restrict__ out) {
  __shared__ unsigned short Ahi[64 * CH_];  // 16 KB
  __shared__ unsigned short Alo[64 * CH_];  // 16 KB
  int tid = threadIdx.x;
  int w = tid >> 6, l = tid & 63;
  int block_row = blockIdx.x * 64;

  const float4* in4 = reinterpret_cast<const float4*>(in) + (size_t)block_row * 32;
  #pragma unroll
  for (int i = 0; i < 8; ++i) {
    int idx = tid + i * 256;
    float4 v = in4[idx];
    int row = idx >> 5;
    int byte = row * 256 + (idx & 31) * 8;
    byte ^= (row & 7) << 4;
    unsigned short h0, l0, h1, l1, h2, l2, h3, l3;
    split_bf16(v.x, h0, l0); split_bf16(v.y, h1, l1);
    split_bf16(v.z, h2, l2); split_bf16(v.w, h3, l3);
    uint2 hp, lp;
    hp.x = (unsigned)h0 | ((unsigned)h1 << 16);
    hp.y = (unsigned)h2 | ((unsigned)h3 << 16);
    lp.x = (unsigned)l0 | ((unsigned)l1 << 16);
    lp.y = (unsigned)l2 | ((unsigned)l3 << 16);
    *reinterpret_cast<uint2*>(reinterpret_cast<char*>(Ahi) + byte) = hp;
    *reinterpret_cast<uint2*>(reinterpret_cast<char*>(Alo) + byte) = lp;
  }
  __syncthreads();

  int arow = 16 * w + (l & 15);
  int kb_off = (l >> 4) * 16;
  bf16x8 a1h[4], a1l[4];
  #pragma unroll
  for (int kb = 0; kb < 4; ++kb) {
    int byte = arow * 256 + kb * 64 + kb_off;
    byte ^= (arow & 7) << 4;
    a1h[kb] = *reinterpret_cast<const bf16x8*>(reinterpret_cast<const char*>(Ahi) + byte);
    a1l[kb] = *reinterpret_cast<const bf16x8*>(reinterpret_cast<const char*>(Alo) + byte);
  }
  __syncthreads();

  int colbase = l & 15;
  int rowoff = (l >> 4) * 4;

  #pragma unroll 2
  for (int cg = 0; cg < 8; ++cg) {
    f32x4 acc1 = {0.f, 0.f, 0.f, 0.f};
    f32x4 acc2 = {0.f, 0.f, 0.f, 0.f};
    #pragma unroll
    for (int kb = 0; kb < 4; ++kb) {
      size_t slot = (size_t)(kb * 8 + cg) * 64 + l;
      bf16x8 bh = *reinterpret_cast<const bf16x8*>(wahi + slot * 8);
      bf16x8 bl = *reinterpret_cast<const bf16x8*>(walo + slot * 8);
      acc1 = __builtin_amdgcn_mfma_f32_16x16x32_bf16(a1h[kb], bh, acc1, 0, 0, 0);
      acc1 = __builtin_amdgcn_mfma_f32_16x16x32_bf16(a1h[kb], bl, acc1, 0, 0, 0);
      acc2 = __builtin_amdgcn_mfma_f32_16x16x32_bf16(a1l[kb], bh, acc2, 0, 0, 0);
    }
    int col = cg * 16 + colbase;
    float bv = ba[col];
    #pragma unroll
    for (int r = 0; r < 4; ++r) {
      float t = fmaxf(acc1[r] + acc2[r] + bv, 0.f);
      int trow = 16 * w + rowoff + r;
      int byte = (trow * 256 + col * 2) ^ ((trow & 7) << 4);
      unsigned short th, tl;
      split_bf16(t, th, tl);
      *reinterpret_cast<unsigned short*>(reinterpret_cast<char*>(Ahi) + byte) = th;
      *reinterpret_cast<unsigned short*>(reinterpret_cast<char*>(Alo) + byte) = tl;
    }
  }
  __syncthreads();

  bf16x8 a2h[4], a2l[4];
  #pragma unroll
  for (int kb = 0; kb < 4; ++kb) {
    int byte = arow * 256 + kb * 64 + kb_off;
    byte ^= (arow & 7) << 4;
    a2h[kb] = *reinterpret_cast<const bf16x8*>(reinterpret_cast<const char*>(Ahi) + byte);
    a2l[kb] = *reinterpret_cast<const bf16x8*>(reinterpret_cast<const char*>(Alo) + byte);
  }
  if (FINAL) __syncthreads();

  float* redf = reinterpret_cast<float*>(Ahi);

  #pragma unroll 2
  for (int cg = 0; cg < 8; ++cg) {
    f32x4 acc1 = {0.f, 0.f, 0.f, 0.f};
    f32x4 acc2 = {0.f, 0.f, 0.f, 0.f};
    #pragma unroll
    for (int kb = 0; kb < 4; ++kb) {
      size_t slot = (size_t)(kb * 8 + cg) * 64 + l;
      bf16x8 bh = *reinterpret_cast<const bf16x8*>(wbhi + slot * 8);
      bf16x8 bl = *reinterpret_cast<const bf16x8*>(wblo + slot * 8);
      acc1 = __builtin_amdgcn_mfma_f32_16x16x32_bf16(a2h[kb], bh, acc1, 0, 0, 0);
      acc1 = __builtin_amdgcn_mfma_f32_16x16x32_bf16(a2h[kb], bl, acc1, 0, 0, 0);
      acc2 = __builtin_amdgcn_mfma_f32_16x16x32_bf16(a2l[kb], bh, acc2, 0, 0, 0);
    }
    int col = cg * 16 + colbase;
    float bv = bb[col];
    if (!FINAL) {
      #pragma unroll
      for (int r = 0; r < 4; ++r) {
        float v = fmaxf(acc1[r] + acc2[r] + bv, 0.f);
        out[(size_t)(block_row + 16 * w + rowoff + r) * CH_ + col] = v;
      }
    } else {
      float part = 0.f;
      #pragma unroll
      for (int r = 0; r < 4; ++r)
        part += fmaxf(acc1[r] + acc2[r] + bv, 0.f);
      redf[(w * 4 + (l >> 4)) * CH_ + col] = part;
    }
  }

  if (FINAL) {
    __syncthreads();
    if (tid < CH_) {
      float tot = 0.f;
      #pragma unroll
      for (int s = 0; s < 16; ++s) tot += redf[s * CH_ + tid];
      int b = block_row / K_;
      atomicAdd(&out[b * CH_ + tid], tot * (1.0f / (float)K_));
    }
  }
}

// ---------------------------------------------------------------------------
// pooled[r] = out1[perm[r]] * topv[r]  (wave per row, float2 lanes, XCD-swz)
// ---------------------------------------------------------------------------
__global__ __launch_bounds__(256) void pool_gather_kernel(
    const float* __restrict__ out1, const int* __restrict__ perm,
    const float* __restrict__ topv, float* __restrict__ pooled) {
  int work = xcd_work<NK_ / 4>(blockIdx.x);
  int r = work * 4 + ((int)threadIdx.x >> 6);
  int lane = threadIdx.x & 63;
  int g = perm[r];
  float v = topv[r];
  float2 t = reinterpret_cast<const float2*>(out1)[(size_t)g * 64 + lane];
  t.x *= v; t.y *= v;
  reinterpret_cast<float2*>(pooled)[(size_t)r * 64 + lane] = t;
}

// ---------------------------------------------------------------------------
extern "C" void kernel_launch(void* const* d_in, const int* in_sizes, int n_in,
                              void* d_out, int out_size, void* d_ws, size_t ws_size,
                              hipStream_t stream) {
  const float* x      = (const float*)d_in[0];
  const int*   eidx   = (const int*)d_in[1];
  const int*   src    = eidx;         // row 0
  const int*   dst    = eidx + E_;    // row 1
  const float* W1 = (const float*)d_in[3];
  const float* b1 = (const float*)d_in[4];
  const float* W2 = (const float*)d_in[5];
  const float* b2 = (const float*)d_in[6];
  const float* w_pool = (const float*)d_in[7];
  const float* W3 = (const float*)d_in[8];
  const float* b3 = (const float*)d_in[9];
  const float* W4 = (const float*)d_in[10];
  const float* b4 = (const float*)d_in[11];
  float* dout = (float*)d_out;

  // ---- workspace carve ----
  char* w = (char*)d_ws;
  auto carve = [&](size_t bytes) {
    char* p = w;
    w += (bytes + 255) & ~(size_t)255;
    return p;
  };
  float*          bufA     = (float*)carve((size_t)NB_ * CH_ * 4);
  float*          bufB     = (float*)carve((size_t)NB_ * CH_ * 4);
  int*            csr1     = (int*)  carve((size_t)E_ * 4);
  int*            csr1t    = (int*)  carve((size_t)E_ * 4);
  int*            ph       = (int*)  carve((size_t)B_ * CPB_ * N_ * 4);  // 2 MB
  int*            offsets1 = (int*)  carve((size_t)(NB_ + 4) * 4);
  float*          scores   = (float*)carve((size_t)NB_ * 4);
  int*            perm     = (int*)  carve((size_t)NK_ * 4);
  float*          topv     = (float*)carve((size_t)NK_ * 4);
  int*            new_idx  = (int*)  carve((size_t)NB_ * 4);
  unsigned short* whiB     = (unsigned short*)carve((size_t)4 * 16384 * 2);
  unsigned short* wloB     = (unsigned short*)carve((size_t)4 * 16384 * 2);
  auto whi = [&](int m) { return whiB + (size_t)m * 16384; };
  auto wlo = [&](int m) { return wloB + (size_t)m * 16384; };

  // zero output accumulator (poisoned 0xAA before every launch)
  hipMemsetAsync(dout, 0, (size_t)B_ * CH_ * 4, stream);

  // ---- weight split + fragment pre-pass ----
  wfrag_kernel<<<32, 256, 0, stream>>>(W1, W2, W3, W4, whiB, wloB);

  // ---- pooling scores + per-graph top-K ----
  scores_kernel<<<NB_ / 4, 256, 0, stream>>>(x, w_pool, scores, NB_);
  topk_kernel<<<B_, 1024, 0, stream>>>(scores, perm, topv, new_idx);

  // ---- chunked CSR build (hist -> scan -> scatter+translate) ----
  csr_hist_kernel<<<B_ * CPB_, 256, 0, stream>>>(dst, ph);
  csr_scan_kernel<<<B_, 1024, 0, stream>>>(ph, offsets1);
  csr_scatter_kernel<<<B_ * CPB_, 256, 0, stream>>>(src, dst, ph, new_idx,
                                                    csr1, csr1t);

  // ---- conv1: aggregate + MFMA MLP pair ----
  aggregate_kernel<<<NB_ / 4, 256, 0, stream>>>(x, offsets1, csr1, bufA);
  gemm_pair_mfma_kernel<false><<<NB_ / 64, 256, 0, stream>>>(
      bufA, whi(0), wlo(0), b1, whi(1), wlo(1), b2, bufB);

  // ---- top-k gather + gate (bufB -> bufA) ----
  pool_gather_kernel<<<NK_ / 4, 256, 0, stream>>>(bufB, perm, topv, bufA);

  // ---- conv2 aggregate from pre-translated csr1t ----
  aggregate2_kernel<<<NK_ / 4, 256, 0, stream>>>(bufA, perm, offsets1, csr1t,
                                                 bufB);

  // ---- conv2 MFMA MLP pair + fused global mean pool ----
  gemm_pair_mfma_kernel<true><<<NK_ / 64, 256, 0, stream>>>(
      bufB, whi(2), wlo(2), b3, whi(3), wlo(3), b4, dout);
}

// Round 12
// 292.280 us; speedup vs baseline: 2.3187x; 1.0802x over previous
//
#include <hip/hip_runtime.h>
#include <hip/hip_bf16.h>

// Problem constants (match reference)
constexpr int B_    = 64;
constexpr int N_    = 1024;
constexpr int DEG_  = 32;
constexpr int CH_   = 128;            // IN_CH == HID == 128
constexpr int E_    = B_ * N_ * DEG_; // 2,097,152 edges
constexpr int NB_   = B_ * N_;        // 65,536 nodes
constexpr int K_    = N_ / 2;         // 512 kept per graph
constexpr int NK_   = B_ * K_;        // 32,768 pooled nodes
constexpr int EPG_  = N_ * DEG_;      // 32,768 edges per graph
constexpr int CPB_  = 16;             // CSR-build chunks per graph
constexpr int CE_   = EPG_ / CPB_;    // 2048 edges per chunk

typedef __attribute__((ext_vector_type(8))) short bf16x8;  // 8 bf16 = 4 VGPRs
typedef __attribute__((ext_vector_type(4))) float f32x4;

// XCD-aware block remap (bijective since nblocks % 8 == 0)
template <int NBLOCKS>
__device__ inline int xcd_work(int bid) {
  return (bid & 7) * (NBLOCKS / 8) + (bid >> 3);
}

// split f32 -> bf16 hi + bf16 lo (RNE), a ~= hi + lo with rel err ~2^-17
__device__ inline void split_bf16(float v, unsigned short& h, unsigned short& l) {
  unsigned u = __float_as_uint(v);
  unsigned hr = (u + 0x7FFFu + ((u >> 16) & 1u)) & 0xFFFF0000u;
  h = (unsigned short)(hr >> 16);
  float d = v - __uint_as_float(hr);
  unsigned ud = __float_as_uint(d);
  l = (unsigned short)((ud + 0x7FFFu + ((ud >> 16) & 1u)) >> 16);
}

// ---------------------------------------------------------------------------
// scores[i] = tanh( dot(x[i], w_pool) / ||w_pool|| )   (wave per node)
// ---------------------------------------------------------------------------
__global__ __launch_bounds__(256) void scores_kernel(
    const float* __restrict__ x, const float* __restrict__ w_pool,
    float* __restrict__ scores, int n) {
  int wave = (blockIdx.x * blockDim.x + threadIdx.x) >> 6;
  int lane = threadIdx.x & 63;
  if (wave >= n) return;
  float w0 = w_pool[lane], w1 = w_pool[64 + lane];
  float a0 = x[(size_t)wave * CH_ + lane];
  float a1 = x[(size_t)wave * CH_ + 64 + lane];
  float dot = a0 * w0 + a1 * w1;
  float nrm = w0 * w0 + w1 * w1;
  #pragma unroll
  for (int m = 32; m > 0; m >>= 1) {
    dot += __shfl_xor(dot, m, 64);
    nrm += __shfl_xor(nrm, m, 64);
  }
  if (lane == 0) scores[wave] = tanhf(dot / sqrtf(nrm));
}

// ---------------------------------------------------------------------------
// Per-graph top-K via bitonic sort of 1024 (score,idx) keys.
// ---------------------------------------------------------------------------
__global__ __launch_bounds__(1024) void topk_kernel(
    const float* __restrict__ scores, int* __restrict__ perm,
    float* __restrict__ topv, int* __restrict__ new_idx) {
  __shared__ unsigned long long keys[N_];
  int b = blockIdx.x, t = threadIdx.x;
  float f = scores[b * N_ + t];
  unsigned u = __float_as_uint(f);
  u = (u & 0x80000000u) ? ~u : (u | 0x80000000u);
  unsigned du = ~u;
  keys[t] = ((unsigned long long)du << 32) | (unsigned)t;
  __syncthreads();
  for (int size = 2; size <= N_; size <<= 1) {
    for (int stride = size >> 1; stride > 0; stride >>= 1) {
      int j = t ^ stride;
      if (j > t) {
        unsigned long long a = keys[t], bk = keys[j];
        bool asc = ((t & size) == 0);
        if ((a > bk) == asc) { keys[t] = bk; keys[j] = a; }
      }
      __syncthreads();
    }
  }
  int idx = (int)(keys[t] & 0xFFFFFFFFu);
  int g = b * N_ + idx;
  if (t < K_) {
    int r = b * K_ + t;
    perm[r] = g;
    topv[r] = scores[g];
    new_idx[g] = r;
  } else {
    new_idx[g] = -1;
  }
}

// ---------------------------------------------------------------------------
// CSR build, chunked (16 chunks/graph = 1024 blocks -> 4 blocks/CU).
// A: per-chunk LDS histogram -> ph[chunk][1024]
// ---------------------------------------------------------------------------
__global__ __launch_bounds__(256) void csr_hist_kernel(
    const int* __restrict__ dst, int* __restrict__ ph) {
  __shared__ int hist[N_];
  int c = blockIdx.x, t = threadIdx.x;
  int b = c >> 4;
  reinterpret_cast<int4*>(hist)[t] = make_int4(0, 0, 0, 0);
  __syncthreads();
  const int ebase = b * EPG_ + (c & 15) * CE_;
  const int4* d4 = reinterpret_cast<const int4*>(dst + ebase);
  #pragma unroll
  for (int i = 0; i < 2; ++i) {
    int4 d = d4[t + i * 256];
    atomicAdd(&hist[d.x - b * N_], 1);
    atomicAdd(&hist[d.y - b * N_], 1);
    atomicAdd(&hist[d.z - b * N_], 1);
    atomicAdd(&hist[d.w - b * N_], 1);
  }
  __syncthreads();
  int4* out4 = reinterpret_cast<int4*>(ph + (size_t)c * N_);
  out4[t] = reinterpret_cast<const int4*>(hist)[t];
}

// ---------------------------------------------------------------------------
// B: per-graph scan. Thread n: chunk-prefix of ph[b*16+q][n], block shfl-scan
// of node totals -> offsets1; overwrite ph with ABSOLUTE chunk-start cursors.
// ---------------------------------------------------------------------------
__global__ __launch_bounds__(1024) void csr_scan_kernel(
    int* __restrict__ ph, int* __restrict__ offsets1) {
  __shared__ int wsum[16];
  int b = blockIdx.x, n = threadIdx.x;
  int c[CPB_], pre[CPB_];
  int tot = 0;
  #pragma unroll
  for (int q = 0; q < CPB_; ++q) {
    c[q] = ph[(size_t)(b * CPB_ + q) * N_ + n];
    pre[q] = tot;
    tot += c[q];
  }
  int lane = n & 63;
  int incl = tot;
  #pragma unroll
  for (int d = 1; d < 64; d <<= 1) {
    int v = __shfl_up(incl, d, 64);
    if (lane >= d) incl += v;
  }
  if (lane == 63) wsum[n >> 6] = incl;
  __syncthreads();
  if (n < 16) {
    int wv = wsum[n];
    int wincl = wv;
    #pragma unroll
    for (int d = 1; d < 16; d <<= 1) {
      int v = __shfl_up(wincl, d, 16);
      if ((n & 15) >= d) wincl += v;
    }
    wsum[n] = wincl - wv;
  }
  __syncthreads();
  int excl = incl - tot + wsum[n >> 6];
  int base = b * EPG_ + excl;
  offsets1[b * N_ + n] = base;
  if (b == 0 && n == 0) offsets1[NB_] = E_;
  #pragma unroll
  for (int q = 0; q < CPB_; ++q)
    ph[(size_t)(b * CPB_ + q) * N_ + n] = base + pre[q];
}

// ---------------------------------------------------------------------------
// C: per-chunk scatter with LDS cursors. ONE packed 4B write per edge:
//   hi 16 bits = local src id (<1024), lo 16 bits = local pooled id (-1/0..511)
// Halves scattered-write cache-line traffic vs two separate arrays.
// ---------------------------------------------------------------------------
__global__ __launch_bounds__(256) void csr_scatter_kernel(
    const int* __restrict__ src, const int* __restrict__ dst,
    const int* __restrict__ ph, const int* __restrict__ new_idx,
    unsigned* __restrict__ csr) {
  __shared__ int cursor[N_];
  int c = blockIdx.x, t = threadIdx.x;
  int b = c >> 4;
  reinterpret_cast<int4*>(cursor)[t] =
      reinterpret_cast<const int4*>(ph + (size_t)c * N_)[t];
  __syncthreads();
  const int ebase = b * EPG_ + (c & 15) * CE_;
  const int nbase = b * N_, kbase = b * K_;
  const int4* s4 = reinterpret_cast<const int4*>(src + ebase);
  const int4* d4 = reinterpret_cast<const int4*>(dst + ebase);
  #pragma unroll
  for (int i = 0; i < 2; ++i) {
    int4 s = s4[t + i * 256];
    int4 d = d4[t + i * 256];
    int n0 = new_idx[s.x], n1 = new_idx[s.y], n2 = new_idx[s.z], n3 = new_idx[s.w];
    unsigned v0 = ((unsigned)(s.x - nbase) << 16) |
                  ((n0 < 0) ? 0xFFFFu : (unsigned)(n0 - kbase));
    unsigned v1 = ((unsigned)(s.y - nbase) << 16) |
                  ((n1 < 0) ? 0xFFFFu : (unsigned)(n1 - kbase));
    unsigned v2 = ((unsigned)(s.z - nbase) << 16) |
                  ((n2 < 0) ? 0xFFFFu : (unsigned)(n2 - kbase));
    unsigned v3 = ((unsigned)(s.w - nbase) << 16) |
                  ((n3 < 0) ? 0xFFFFu : (unsigned)(n3 - kbase));
    int p0 = atomicAdd(&cursor[d.x - nbase], 1); csr[p0] = v0;
    int p1 = atomicAdd(&cursor[d.y - nbase], 1); csr[p1] = v1;
    int p2 = atomicAdd(&cursor[d.z - nbase], 1); csr[p2] = v2;
    int p3 = atomicAdd(&cursor[d.w - nbase], 1); csr[p3] = v3;
  }
}

// ---------------------------------------------------------------------------
// Pre-split + pre-fragment the 4 weight matrices into per-lane MFMA B-frag
// order (see round-9 notes). 128 waves total.
// ---------------------------------------------------------------------------
__global__ __launch_bounds__(256) void wfrag_kernel(
    const float* __restrict__ W1, const float* __restrict__ W2,
    const float* __restrict__ W3, const float* __restrict__ W4,
    unsigned short* __restrict__ whi, unsigned short* __restrict__ wlo) {
  int wid = (blockIdx.x * 256 + (int)threadIdx.x) >> 6;  // 0..127
  int l = threadIdx.x & 63;
  const float* Ws[4] = {W1, W2, W3, W4};
  int mat = wid >> 5, kb = (wid >> 3) & 3, cg = wid & 7;
  const float* W = Ws[mat];
  int col = cg * 16 + (l & 15);
  int kbase = kb * 32 + (l >> 4) * 8;
  bf16x8 hv, lv;
  #pragma unroll
  for (int j = 0; j < 8; ++j) {
    unsigned short h, lo;
    split_bf16(W[(size_t)(kbase + j) * CH_ + col], h, lo);
    hv[j] = (short)h; lv[j] = (short)lo;
  }
  size_t slot = ((size_t)mat * 32 + (size_t)(kb * 8 + cg)) * 64 + l;
  *reinterpret_cast<bf16x8*>(whi + slot * 8) = hv;
  *reinterpret_cast<bf16x8*>(wlo + slot * 8) = lv;
}

// ---------------------------------------------------------------------------
// conv1 aggregate (paired-row float4 gathers, XCD-swizzled), packed csr:
// neighbor global id = graph_base + (csr[p] >> 16).
// ---------------------------------------------------------------------------
__global__ __launch_bounds__(256) void aggregate_kernel(
    const float* __restrict__ feat, const int* __restrict__ offs,
    const unsigned* __restrict__ srcs, float* __restrict__ out) {
  int work = xcd_work<NB_ / 4>(blockIdx.x);
  int node = work * 4 + ((int)threadIdx.x >> 6);
  int lane = threadIdx.x & 63;
  int h = lane >> 5, li = lane & 31;
  int gbase = (node >> 10) << 10;     // graph node base
  const float4* f4 = reinterpret_cast<const float4*>(feat);
  int s = offs[node], e = offs[node + 1];
  int total = (e - s) + 1;            // +1 for self
  float4 acc = make_float4(0.f, 0.f, 0.f, 0.f);
  int i = 0;
  if (total >= 2) {                   // first pair = (self, elem1)
    int j = h ? (gbase + (int)(srcs[s] >> 16)) : node;
    acc = f4[(size_t)j * 32 + li];
    i = 2;
  }
  for (; i + 4 <= total; i += 4) {
    int ja = gbase + (int)(srcs[s + (h ? i : i - 1)] >> 16);
    int jb = gbase + (int)(srcs[s + (h ? i + 2 : i + 1)] >> 16);
    float4 va = f4[(size_t)ja * 32 + li];
    float4 vb = f4[(size_t)jb * 32 + li];
    acc.x += va.x + vb.x; acc.y += va.y + vb.y;
    acc.z += va.z + vb.z; acc.w += va.w + vb.w;
  }
  for (; i + 2 <= total; i += 2) {
    int j = gbase + (int)(srcs[s + (h ? i : i - 1)] >> 16);
    float4 v = f4[(size_t)j * 32 + li];
    acc.x += v.x; acc.y += v.y; acc.z += v.z; acc.w += v.w;
  }
  if (i < total) {                    // odd leftover -> half-wave load
    if (h == 0) {
      int j = (i == 0) ? node : (gbase + (int)(srcs[s + i - 1] >> 16));
      float4 v = f4[(size_t)j * 32 + li];
      acc.x += v.x; acc.y += v.y; acc.z += v.z; acc.w += v.w;
    }
  }
  acc.x += __shfl_xor(acc.x, 32, 64);
  acc.y += __shfl_xor(acc.y, 32, 64);
  acc.z += __shfl_xor(acc.z, 32, 64);
  acc.w += __shfl_xor(acc.w, 32, 64);
  if (h == 0)
    reinterpret_cast<float4*>(out)[(size_t)node * 32 + li] = acc;
}

// ---------------------------------------------------------------------------
// conv2 aggregate from packed csr low half: local pooled id or -1.
// 4-wide unrolled predicated float2 loads (independent gather chains).
// ---------------------------------------------------------------------------
__global__ __launch_bounds__(256) void aggregate2_kernel(
    const float* __restrict__ pooled, const int* __restrict__ perm,
    const int* __restrict__ offs1, const unsigned* __restrict__ csr,
    float* __restrict__ out) {
  int work = xcd_work<NK_ / 4>(blockIdx.x);
  int r = work * 4 + ((int)threadIdx.x >> 6);
  int lane = threadIdx.x & 63;
  int kbase = (r >> 9) << 9;          // graph pooled base = b*K_
  const float2* f2 = reinterpret_cast<const float2*>(pooled);
  int g = perm[r];
  int s = offs1[g], e = offs1[g + 1];
  float2 acc = f2[(size_t)r * 64 + lane];
  int p = s;
  for (; p + 4 <= e; p += 4) {
    short n0 = (short)(csr[p]     & 0xFFFFu);
    short n1 = (short)(csr[p + 1] & 0xFFFFu);
    short n2 = (short)(csr[p + 2] & 0xFFFFu);
    short n3 = (short)(csr[p + 3] & 0xFFFFu);
    if (n0 >= 0) { float2 v = f2[(size_t)(kbase + n0) * 64 + lane]; acc.x += v.x; acc.y += v.y; }
    if (n1 >= 0) { float2 v = f2[(size_t)(kbase + n1) * 64 + lane]; acc.x += v.x; acc.y += v.y; }
    if (n2 >= 0) { float2 v = f2[(size_t)(kbase + n2) * 64 + lane]; acc.x += v.x; acc.y += v.y; }
    if (n3 >= 0) { float2 v = f2[(size_t)(kbase + n3) * 64 + lane]; acc.x += v.x; acc.y += v.y; }
  }
  for (; p < e; ++p) {
    short n0 = (short)(csr[p] & 0xFFFFu);
    if (n0 >= 0) { float2 v = f2[(size_t)(kbase + n0) * 64 + lane]; acc.x += v.x; acc.y += v.y; }
  }
  reinterpret_cast<float2*>(out)[(size_t)r * 64 + lane] = acc;
}

// ---------------------------------------------------------------------------
// MFMA split-bf16 GEMM pair (unchanged; verified absmax 0.0625)
// ---------------------------------------------------------------------------
template <bool FINAL>
__global__ __launch_bounds__(256) void gemm_pair_mfma_kernel(
    const float* __restrict__ in,
    const unsigned short* __restrict__ wahi, const unsigned short* __restrict__ walo,
    const float* __restrict__ ba,
    const unsigned short* __restrict__ wbhi, const unsigned short* __restrict__ wblo,
    const float* __restrict__ bb,
    float* __restrict__ out) {
  __shared__ unsigned short Ahi[64 * CH_];  // 16 KB
  __shared__ unsigned short Alo[64 * CH_];  // 16 KB
  int tid = threadIdx.x;
  int w = tid >> 6, l = tid & 63;
  int block_row = blockIdx.x * 64;

  const float4* in4 = reinterpret_cast<const float4*>(in) + (size_t)block_row * 32;
  #pragma unroll
  for (int i = 0; i < 8; ++i) {
    int idx = tid + i * 256;
    float4 v = in4[idx];
    int row = idx >> 5;
    int byte = row * 256 + (idx & 31) * 8;
    byte ^= (row & 7) << 4;
    unsigned short h0, l0, h1, l1, h2, l2, h3, l3;
    split_bf16(v.x, h0, l0); split_bf16(v.y, h1, l1);
    split_bf16(v.z, h2, l2); split_bf16(v.w, h3, l3);
    uint2 hp, lp;
    hp.x = (unsigned)h0 | ((unsigned)h1 << 16);
    hp.y = (unsigned)h2 | ((unsigned)h3 << 16);
    lp.x = (unsigned)l0 | ((unsigned)l1 << 16);
    lp.y = (unsigned)l2 | ((unsigned)l3 << 16);
    *reinterpret_cast<uint2*>(reinterpret_cast<char*>(Ahi) + byte) = hp;
    *reinterpret_cast<uint2*>(reinterpret_cast<char*>(Alo) + byte) = lp;
  }
  __syncthreads();

  int arow = 16 * w + (l & 15);
  int kb_off = (l >> 4) * 16;
  bf16x8 a1h[4], a1l[4];
  #pragma unroll
  for (int kb = 0; kb < 4; ++kb) {
    int byte = arow * 256 + kb * 64 + kb_off;
    byte ^= (arow & 7) << 4;
    a1h[kb] = *reinterpret_cast<const bf16x8*>(reinterpret_cast<const char*>(Ahi) + byte);
    a1l[kb] = *reinterpret_cast<const bf16x8*>(reinterpret_cast<const char*>(Alo) + byte);
  }
  __syncthreads();

  int colbase = l & 15;
  int rowoff = (l >> 4) * 4;

  #pragma unroll 2
  for (int cg = 0; cg < 8; ++cg) {
    f32x4 acc1 = {0.f, 0.f, 0.f, 0.f};
    f32x4 acc2 = {0.f, 0.f, 0.f, 0.f};
    #pragma unroll
    for (int kb = 0; kb < 4; ++kb) {
      size_t slot = (size_t)(kb * 8 + cg) * 64 + l;
      bf16x8 bh = *reinterpret_cast<const bf16x8*>(wahi + slot * 8);
      bf16x8 bl = *reinterpret_cast<const bf16x8*>(walo + slot * 8);
      acc1 = __builtin_amdgcn_mfma_f32_16x16x32_bf16(a1h[kb], bh, acc1, 0, 0, 0);
      acc1 = __builtin_amdgcn_mfma_f32_16x16x32_bf16(a1h[kb], bl, acc1, 0, 0, 0);
      acc2 = __builtin_amdgcn_mfma_f32_16x16x32_bf16(a1l[kb], bh, acc2, 0, 0, 0);
    }
    int col = cg * 16 + colbase;
    float bv = ba[col];
    #pragma unroll
    for (int r = 0; r < 4; ++r) {
      float t = fmaxf(acc1[r] + acc2[r] + bv, 0.f);
      int trow = 16 * w + rowoff + r;
      int byte = (trow * 256 + col * 2) ^ ((trow & 7) << 4);
      unsigned short th, tl;
      split_bf16(t, th, tl);
      *reinterpret_cast<unsigned short*>(reinterpret_cast<char*>(Ahi) + byte) = th;
      *reinterpret_cast<unsigned short*>(reinterpret_cast<char*>(Alo) + byte) = tl;
    }
  }
  __syncthreads();

  bf16x8 a2h[4], a2l[4];
  #pragma unroll
  for (int kb = 0; kb < 4; ++kb) {
    int byte = arow * 256 + kb * 64 + kb_off;
    byte ^= (arow & 7) << 4;
    a2h[kb] = *reinterpret_cast<const bf16x8*>(reinterpret_cast<const char*>(Ahi) + byte);
    a2l[kb] = *reinterpret_cast<const bf16x8*>(reinterpret_cast<const char*>(Alo) + byte);
  }
  if (FINAL) __syncthreads();

  float* redf = reinterpret_cast<float*>(Ahi);

  #pragma unroll 2
  for (int cg = 0; cg < 8; ++cg) {
    f32x4 acc1 = {0.f, 0.f, 0.f, 0.f};
    f32x4 acc2 = {0.f, 0.f, 0.f, 0.f};
    #pragma unroll
    for (int kb = 0; kb < 4; ++kb) {
      size_t slot = (size_t)(kb * 8 + cg) * 64 + l;
      bf16x8 bh = *reinterpret_cast<const bf16x8*>(wbhi + slot * 8);
      bf16x8 bl = *reinterpret_cast<const bf16x8*>(wblo + slot * 8);
      acc1 = __builtin_amdgcn_mfma_f32_16x16x32_bf16(a2h[kb], bh, acc1, 0, 0, 0);
      acc1 = __builtin_amdgcn_mfma_f32_16x16x32_bf16(a2h[kb], bl, acc1, 0, 0, 0);
      acc2 = __builtin_amdgcn_mfma_f32_16x16x32_bf16(a2l[kb], bh, acc2, 0, 0, 0);
    }
    int col = cg * 16 + colbase;
    float bv = bb[col];
    if (!FINAL) {
      #pragma unroll
      for (int r = 0; r < 4; ++r) {
        float v = fmaxf(acc1[r] + acc2[r] + bv, 0.f);
        out[(size_t)(block_row + 16 * w + rowoff + r) * CH_ + col] = v;
      }
    } else {
      float part = 0.f;
      #pragma unroll
      for (int r = 0; r < 4; ++r)
        part += fmaxf(acc1[r] + acc2[r] + bv, 0.f);
      redf[(w * 4 + (l >> 4)) * CH_ + col] = part;
    }
  }

  if (FINAL) {
    __syncthreads();
    if (tid < CH_) {
      float tot = 0.f;
      #pragma unroll
      for (int s = 0; s < 16; ++s) tot += redf[s * CH_ + tid];
      int b = block_row / K_;
      atomicAdd(&out[b * CH_ + tid], tot * (1.0f / (float)K_));
    }
  }
}

// ---------------------------------------------------------------------------
// pooled[r] = out1[perm[r]] * topv[r]  (wave per row, float2 lanes, XCD-swz)
// ---------------------------------------------------------------------------
__global__ __launch_bounds__(256) void pool_gather_kernel(
    const float* __restrict__ out1, const int* __restrict__ perm,
    const float* __restrict__ topv, float* __restrict__ pooled) {
  int work = xcd_work<NK_ / 4>(blockIdx.x);
  int r = work * 4 + ((int)threadIdx.x >> 6);
  int lane = threadIdx.x & 63;
  int g = perm[r];
  float v = topv[r];
  float2 t = reinterpret_cast<const float2*>(out1)[(size_t)g * 64 + lane];
  t.x *= v; t.y *= v;
  reinterpret_cast<float2*>(pooled)[(size_t)r * 64 + lane] = t;
}

// ---------------------------------------------------------------------------
extern "C" void kernel_launch(void* const* d_in, const int* in_sizes, int n_in,
                              void* d_out, int out_size, void* d_ws, size_t ws_size,
                              hipStream_t stream) {
  const float* x      = (const float*)d_in[0];
  const int*   eidx   = (const int*)d_in[1];
  const int*   src    = eidx;         // row 0
  const int*   dst    = eidx + E_;    // row 1
  const float* W1 = (const float*)d_in[3];
  const float* b1 = (const float*)d_in[4];
  const float* W2 = (const float*)d_in[5];
  const float* b2 = (const float*)d_in[6];
  const float* w_pool = (const float*)d_in[7];
  const float* W3 = (const float*)d_in[8];
  const float* b3 = (const float*)d_in[9];
  const float* W4 = (const float*)d_in[10];
  const float* b4 = (const float*)d_in[11];
  float* dout = (float*)d_out;

  // ---- workspace carve ----
  char* w = (char*)d_ws;
  auto carve = [&](size_t bytes) {
    char* p = w;
    w += (bytes + 255) & ~(size_t)255;
    return p;
  };
  float*          bufA     = (float*)carve((size_t)NB_ * CH_ * 4);
  float*          bufB     = (float*)carve((size_t)NB_ * CH_ * 4);
  unsigned*       csr      = (unsigned*)carve((size_t)E_ * 4);
  int*            ph       = (int*)  carve((size_t)B_ * CPB_ * N_ * 4);  // 4 MB
  int*            offsets1 = (int*)  carve((size_t)(NB_ + 4) * 4);
  float*          scores   = (float*)carve((size_t)NB_ * 4);
  int*            perm     = (int*)  carve((size_t)NK_ * 4);
  float*          topv     = (float*)carve((size_t)NK_ * 4);
  int*            new_idx  = (int*)  carve((size_t)NB_ * 4);
  unsigned short* whiB     = (unsigned short*)carve((size_t)4 * 16384 * 2);
  unsigned short* wloB     = (unsigned short*)carve((size_t)4 * 16384 * 2);
  auto whi = [&](int m) { return whiB + (size_t)m * 16384; };
  auto wlo = [&](int m) { return wloB + (size_t)m * 16384; };

  // zero output accumulator (poisoned 0xAA before every launch)
  hipMemsetAsync(dout, 0, (size_t)B_ * CH_ * 4, stream);

  // ---- weight split + fragment pre-pass ----
  wfrag_kernel<<<32, 256, 0, stream>>>(W1, W2, W3, W4, whiB, wloB);

  // ---- pooling scores + per-graph top-K ----
  scores_kernel<<<NB_ / 4, 256, 0, stream>>>(x, w_pool, scores, NB_);
  topk_kernel<<<B_, 1024, 0, stream>>>(scores, perm, topv, new_idx);

  // ---- chunked CSR build (hist -> scan -> packed scatter) ----
  csr_hist_kernel<<<B_ * CPB_, 256, 0, stream>>>(dst, ph);
  csr_scan_kernel<<<B_, 1024, 0, stream>>>(ph, offsets1);
  csr_scatter_kernel<<<B_ * CPB_, 256, 0, stream>>>(src, dst, ph, new_idx, csr);

  // ---- conv1: aggregate + MFMA MLP pair ----
  aggregate_kernel<<<NB_ / 4, 256, 0, stream>>>(x, offsets1, csr, bufA);
  gemm_pair_mfma_kernel<false><<<NB_ / 64, 256, 0, stream>>>(
      bufA, whi(0), wlo(0), b1, whi(1), wlo(1), b2, bufB);

  // ---- top-k gather + gate (bufB -> bufA) ----
  pool_gather_kernel<<<NK_ / 4, 256, 0, stream>>>(bufB, perm, topv, bufA);

  // ---- conv2 aggregate from packed csr ----
  aggregate2_kernel<<<NK_ / 4, 256, 0, stream>>>(bufA, perm, offsets1, csr, bufB);

  // ---- conv2 MFMA MLP pair + fused global mean pool ----
  gemm_pair_mfma_kernel<true><<<NK_ / 64, 256, 0, stream>>>(
      bufB, whi(2), wlo(2), b3, whi(3), wlo(3), b4, dout);
}

// Round 13
// 266.939 us; speedup vs baseline: 2.5388x; 1.0949x over previous
//
#include <hip/hip_runtime.h>
#include <hip/hip_bf16.h>

// Problem constants (match reference)
constexpr int B_    = 64;
constexpr int N_    = 1024;
constexpr int DEG_  = 32;
constexpr int CH_   = 128;            // IN_CH == HID == 128
constexpr int E_    = B_ * N_ * DEG_; // 2,097,152 edges
constexpr int NB_   = B_ * N_;        // 65,536 nodes
constexpr int K_    = N_ / 2;         // 512 kept per graph
constexpr int NK_   = B_ * K_;        // 32,768 pooled nodes
constexpr int EPG_  = N_ * DEG_;      // 32,768 edges per graph
constexpr int CPB_  = 16;             // CSR-build chunks per graph
constexpr int CE_   = EPG_ / CPB_;    // 2048 edges per chunk
constexpr int MAXD_ = 112;            // per-node compacted-list bound (mean 16+1, 11+ sigma)

typedef __attribute__((ext_vector_type(8))) short bf16x8;  // 8 bf16 = 4 VGPRs
typedef __attribute__((ext_vector_type(4))) float f32x4;

// XCD-aware block remap (bijective since nblocks % 8 == 0)
template <int NBLOCKS>
__device__ inline int xcd_work(int bid) {
  return (bid & 7) * (NBLOCKS / 8) + (bid >> 3);
}

// split f32 -> bf16 hi + bf16 lo (RNE), a ~= hi + lo with rel err ~2^-17
__device__ inline void split_bf16(float v, unsigned short& h, unsigned short& l) {
  unsigned u = __float_as_uint(v);
  unsigned hr = (u + 0x7FFFu + ((u >> 16) & 1u)) & 0xFFFF0000u;
  h = (unsigned short)(hr >> 16);
  float d = v - __uint_as_float(hr);
  unsigned ud = __float_as_uint(d);
  l = (unsigned short)((ud + 0x7FFFu + ((ud >> 16) & 1u)) >> 16);
}

// ---------------------------------------------------------------------------
// scores[i] = tanh( dot(x[i], w_pool) / ||w_pool|| )   (wave per node)
// ---------------------------------------------------------------------------
__global__ __launch_bounds__(256) void scores_kernel(
    const float* __restrict__ x, const float* __restrict__ w_pool,
    float* __restrict__ scores, int n) {
  int wave = (blockIdx.x * blockDim.x + threadIdx.x) >> 6;
  int lane = threadIdx.x & 63;
  if (wave >= n) return;
  float w0 = w_pool[lane], w1 = w_pool[64 + lane];
  float a0 = x[(size_t)wave * CH_ + lane];
  float a1 = x[(size_t)wave * CH_ + 64 + lane];
  float dot = a0 * w0 + a1 * w1;
  float nrm = w0 * w0 + w1 * w1;
  #pragma unroll
  for (int m = 32; m > 0; m >>= 1) {
    dot += __shfl_xor(dot, m, 64);
    nrm += __shfl_xor(nrm, m, 64);
  }
  if (lane == 0) scores[wave] = tanhf(dot / sqrtf(nrm));
}

// ---------------------------------------------------------------------------
// Per-graph top-K via bitonic sort of 1024 (score,idx) keys.
// ---------------------------------------------------------------------------
__global__ __launch_bounds__(1024) void topk_kernel(
    const float* __restrict__ scores, int* __restrict__ perm,
    float* __restrict__ topv, int* __restrict__ new_idx) {
  __shared__ unsigned long long keys[N_];
  int b = blockIdx.x, t = threadIdx.x;
  float f = scores[b * N_ + t];
  unsigned u = __float_as_uint(f);
  u = (u & 0x80000000u) ? ~u : (u | 0x80000000u);
  unsigned du = ~u;
  keys[t] = ((unsigned long long)du << 32) | (unsigned)t;
  __syncthreads();
  for (int size = 2; size <= N_; size <<= 1) {
    for (int stride = size >> 1; stride > 0; stride >>= 1) {
      int j = t ^ stride;
      if (j > t) {
        unsigned long long a = keys[t], bk = keys[j];
        bool asc = ((t & size) == 0);
        if ((a > bk) == asc) { keys[t] = bk; keys[j] = a; }
      }
      __syncthreads();
    }
  }
  int idx = (int)(keys[t] & 0xFFFFFFFFu);
  int g = b * N_ + idx;
  if (t < K_) {
    int r = b * K_ + t;
    perm[r] = g;
    topv[r] = scores[g];
    new_idx[g] = r;
  } else {
    new_idx[g] = -1;
  }
}

// ---------------------------------------------------------------------------
// CSR build, chunked (16 chunks/graph = 1024 blocks -> 4 blocks/CU).
// A: per-chunk LDS histogram -> ph[chunk][1024]
// ---------------------------------------------------------------------------
__global__ __launch_bounds__(256) void csr_hist_kernel(
    const int* __restrict__ dst, int* __restrict__ ph) {
  __shared__ int hist[N_];
  int c = blockIdx.x, t = threadIdx.x;
  int b = c >> 4;
  reinterpret_cast<int4*>(hist)[t] = make_int4(0, 0, 0, 0);
  __syncthreads();
  const int ebase = b * EPG_ + (c & 15) * CE_;
  const int4* d4 = reinterpret_cast<const int4*>(dst + ebase);
  #pragma unroll
  for (int i = 0; i < 2; ++i) {
    int4 d = d4[t + i * 256];
    atomicAdd(&hist[d.x - b * N_], 1);
    atomicAdd(&hist[d.y - b * N_], 1);
    atomicAdd(&hist[d.z - b * N_], 1);
    atomicAdd(&hist[d.w - b * N_], 1);
  }
  __syncthreads();
  int4* out4 = reinterpret_cast<int4*>(ph + (size_t)c * N_);
  out4[t] = reinterpret_cast<const int4*>(hist)[t];
}

// ---------------------------------------------------------------------------
// B: per-graph scan. Thread n: chunk-prefix of ph[b*16+q][n], block shfl-scan
// of node totals -> offsets1; overwrite ph with ABSOLUTE chunk-start cursors.
// ---------------------------------------------------------------------------
__global__ __launch_bounds__(1024) void csr_scan_kernel(
    int* __restrict__ ph, int* __restrict__ offsets1) {
  __shared__ int wsum[16];
  int b = blockIdx.x, n = threadIdx.x;
  int c[CPB_], pre[CPB_];
  int tot = 0;
  #pragma unroll
  for (int q = 0; q < CPB_; ++q) {
    c[q] = ph[(size_t)(b * CPB_ + q) * N_ + n];
    pre[q] = tot;
    tot += c[q];
  }
  int lane = n & 63;
  int incl = tot;
  #pragma unroll
  for (int d = 1; d < 64; d <<= 1) {
    int v = __shfl_up(incl, d, 64);
    if (lane >= d) incl += v;
  }
  if (lane == 63) wsum[n >> 6] = incl;
  __syncthreads();
  if (n < 16) {
    int wv = wsum[n];
    int wincl = wv;
    #pragma unroll
    for (int d = 1; d < 16; d <<= 1) {
      int v = __shfl_up(wincl, d, 16);
      if ((n & 15) >= d) wincl += v;
    }
    wsum[n] = wincl - wv;
  }
  __syncthreads();
  int excl = incl - tot + wsum[n >> 6];
  int base = b * EPG_ + excl;
  offsets1[b * N_ + n] = base;
  if (b == 0 && n == 0) offsets1[NB_] = E_;
  #pragma unroll
  for (int q = 0; q < CPB_; ++q)
    ph[(size_t)(b * CPB_ + q) * N_ + n] = base + pre[q];
}

// ---------------------------------------------------------------------------
// C: per-chunk scatter with LDS cursors. ONE packed 4B write per edge:
//   hi 16 bits = local src id (<1024), lo 16 bits = local pooled id (-1/0..511)
// ---------------------------------------------------------------------------
__global__ __launch_bounds__(256) void csr_scatter_kernel(
    const int* __restrict__ src, const int* __restrict__ dst,
    const int* __restrict__ ph, const int* __restrict__ new_idx,
    unsigned* __restrict__ csr) {
  __shared__ int cursor[N_];
  int c = blockIdx.x, t = threadIdx.x;
  int b = c >> 4;
  reinterpret_cast<int4*>(cursor)[t] =
      reinterpret_cast<const int4*>(ph + (size_t)c * N_)[t];
  __syncthreads();
  const int ebase = b * EPG_ + (c & 15) * CE_;
  const int nbase = b * N_, kbase = b * K_;
  const int4* s4 = reinterpret_cast<const int4*>(src + ebase);
  const int4* d4 = reinterpret_cast<const int4*>(dst + ebase);
  #pragma unroll
  for (int i = 0; i < 2; ++i) {
    int4 s = s4[t + i * 256];
    int4 d = d4[t + i * 256];
    int n0 = new_idx[s.x], n1 = new_idx[s.y], n2 = new_idx[s.z], n3 = new_idx[s.w];
    unsigned v0 = ((unsigned)(s.x - nbase) << 16) |
                  ((n0 < 0) ? 0xFFFFu : (unsigned)(n0 - kbase));
    unsigned v1 = ((unsigned)(s.y - nbase) << 16) |
                  ((n1 < 0) ? 0xFFFFu : (unsigned)(n1 - kbase));
    unsigned v2 = ((unsigned)(s.z - nbase) << 16) |
                  ((n2 < 0) ? 0xFFFFu : (unsigned)(n2 - kbase));
    unsigned v3 = ((unsigned)(s.w - nbase) << 16) |
                  ((n3 < 0) ? 0xFFFFu : (unsigned)(n3 - kbase));
    int p0 = atomicAdd(&cursor[d.x - nbase], 1); csr[p0] = v0;
    int p1 = atomicAdd(&cursor[d.y - nbase], 1); csr[p1] = v1;
    int p2 = atomicAdd(&cursor[d.z - nbase], 1); csr[p2] = v2;
    int p3 = atomicAdd(&cursor[d.w - nbase], 1); csr[p3] = v3;
  }
}

// ---------------------------------------------------------------------------
// Pre-split + pre-fragment the 4 weight matrices into per-lane MFMA B-frag
// order (see round-9 notes). 128 waves total.
// ---------------------------------------------------------------------------
__global__ __launch_bounds__(256) void wfrag_kernel(
    const float* __restrict__ W1, const float* __restrict__ W2,
    const float* __restrict__ W3, const float* __restrict__ W4,
    unsigned short* __restrict__ whi, unsigned short* __restrict__ wlo) {
  int wid = (blockIdx.x * 256 + (int)threadIdx.x) >> 6;  // 0..127
  int l = threadIdx.x & 63;
  const float* Ws[4] = {W1, W2, W3, W4};
  int mat = wid >> 5, kb = (wid >> 3) & 3, cg = wid & 7;
  const float* W = Ws[mat];
  int col = cg * 16 + (l & 15);
  int kbase = kb * 32 + (l >> 4) * 8;
  bf16x8 hv, lv;
  #pragma unroll
  for (int j = 0; j < 8; ++j) {
    unsigned short h, lo;
    split_bf16(W[(size_t)(kbase + j) * CH_ + col], h, lo);
    hv[j] = (short)h; lv[j] = (short)lo;
  }
  size_t slot = ((size_t)mat * 32 + (size_t)(kb * 8 + cg)) * 64 + l;
  *reinterpret_cast<bf16x8*>(whi + slot * 8) = hv;
  *reinterpret_cast<bf16x8*>(wlo + slot * 8) = lv;
}

// ---------------------------------------------------------------------------
// conv1 aggregate (paired-row float4 gathers, XCD-swizzled), packed csr.
// QUAD-unrolled: 4 paired loads (8 rows) in flight per iteration.
// ---------------------------------------------------------------------------
__global__ __launch_bounds__(256) void aggregate_kernel(
    const float* __restrict__ feat, const int* __restrict__ offs,
    const unsigned* __restrict__ srcs, float* __restrict__ out) {
  int work = xcd_work<NB_ / 4>(blockIdx.x);
  int node = work * 4 + ((int)threadIdx.x >> 6);
  int lane = threadIdx.x & 63;
  int h = lane >> 5, li = lane & 31;
  int gbase = (node >> 10) << 10;     // graph node base
  const float4* f4 = reinterpret_cast<const float4*>(feat);
  int s = offs[node], e = offs[node + 1];
  int total = (e - s) + 1;            // +1 for self
  float4 acc = make_float4(0.f, 0.f, 0.f, 0.f);
  int i = 0;
  if (total >= 2) {                   // first pair = (self, elem1)
    int j = h ? (gbase + (int)(srcs[s] >> 16)) : node;
    acc = f4[(size_t)j * 32 + li];
    i = 2;
  }
  // element k (k>=1) lives at srcs[s+k-1]; pair = elems (i, i+1)
  for (; i + 8 <= total; i += 8) {    // 4 pairs (8 rows) in flight
    int j0 = gbase + (int)(srcs[s + (h ? i     : i - 1)] >> 16);
    int j1 = gbase + (int)(srcs[s + (h ? i + 2 : i + 1)] >> 16);
    int j2 = gbase + (int)(srcs[s + (h ? i + 4 : i + 3)] >> 16);
    int j3 = gbase + (int)(srcs[s + (h ? i + 6 : i + 5)] >> 16);
    float4 v0 = f4[(size_t)j0 * 32 + li];
    float4 v1 = f4[(size_t)j1 * 32 + li];
    float4 v2 = f4[(size_t)j2 * 32 + li];
    float4 v3 = f4[(size_t)j3 * 32 + li];
    acc.x += (v0.x + v1.x) + (v2.x + v3.x);
    acc.y += (v0.y + v1.y) + (v2.y + v3.y);
    acc.z += (v0.z + v1.z) + (v2.z + v3.z);
    acc.w += (v0.w + v1.w) + (v2.w + v3.w);
  }
  for (; i + 4 <= total; i += 4) {    // 2 pairs
    int ja = gbase + (int)(srcs[s + (h ? i : i - 1)] >> 16);
    int jb = gbase + (int)(srcs[s + (h ? i + 2 : i + 1)] >> 16);
    float4 va = f4[(size_t)ja * 32 + li];
    float4 vb = f4[(size_t)jb * 32 + li];
    acc.x += va.x + vb.x; acc.y += va.y + vb.y;
    acc.z += va.z + vb.z; acc.w += va.w + vb.w;
  }
  for (; i + 2 <= total; i += 2) {    // 1 pair
    int j = gbase + (int)(srcs[s + (h ? i : i - 1)] >> 16);
    float4 v = f4[(size_t)j * 32 + li];
    acc.x += v.x; acc.y += v.y; acc.z += v.z; acc.w += v.w;
  }
  if (i < total) {                    // odd leftover -> half-wave load
    if (h == 0) {
      int j = (i == 0) ? node : (gbase + (int)(srcs[s + i - 1] >> 16));
      float4 v = f4[(size_t)j * 32 + li];
      acc.x += v.x; acc.y += v.y; acc.z += v.z; acc.w += v.w;
    }
  }
  acc.x += __shfl_xor(acc.x, 32, 64);
  acc.y += __shfl_xor(acc.y, 32, 64);
  acc.z += __shfl_xor(acc.z, 32, 64);
  acc.w += __shfl_xor(acc.w, 32, 64);
  if (h == 0)
    reinterpret_cast<float4*>(out)[(size_t)node * 32 + li] = acc;
}

// ---------------------------------------------------------------------------
// conv2 aggregate: COMPACT-then-GATHER. Per wave: coalesced read of the
// packed csr bucket, ballot+prefix-popcount compact of valid pooled ids
// (self seeded first) into LDS, then paired-row float4 quad-unrolled gather
// (1KB/instr, no predication in the hot loop).
// ---------------------------------------------------------------------------
__global__ __launch_bounds__(256) void aggregate2_kernel(
    const float* __restrict__ pooled, const int* __restrict__ perm,
    const int* __restrict__ offs1, const unsigned* __restrict__ csr,
    float* __restrict__ out) {
  __shared__ int ids[4][MAXD_];
  int work = xcd_work<NK_ / 4>(blockIdx.x);
  int wv = (int)threadIdx.x >> 6;
  int r = work * 4 + wv;
  int lane = threadIdx.x & 63;
  int h = lane >> 5, li = lane & 31;
  int kbase = (r >> 9) << 9;          // graph pooled base = b*K_
  int g = perm[r];
  int s = offs1[g], e = offs1[g + 1];
  int deg = e - s;
  // ---- compact valid neighbor ids (self first) ----
  if (lane == 0) ids[wv][0] = r;
  int m = 1;
  for (int base = 0; base < deg; base += 64) {
    int idx = base + lane;
    bool val = false;
    int id = 0;
    if (idx < deg) {
      short nl = (short)(csr[s + idx] & 0xFFFFu);
      val = nl >= 0;
      id = kbase + nl;
    }
    unsigned long long mask = __ballot(val);
    if (val) {
      int pos = m + __popcll(mask & ((1ull << lane) - 1ull));
      ids[wv][pos] = id;
    }
    m += __popcll(mask);
  }
  // same-wave LDS write->read: lockstep, compiler inserts lgkmcnt waits
  // ---- paired-row float4 gather over compacted list ----
  const float4* f4 = reinterpret_cast<const float4*>(pooled);
  float4 acc = make_float4(0.f, 0.f, 0.f, 0.f);
  int i = 0;
  for (; i + 8 <= m; i += 8) {        // 4 pairs (8 rows) in flight
    int j0 = ids[wv][i     + h];
    int j1 = ids[wv][i + 2 + h];
    int j2 = ids[wv][i + 4 + h];
    int j3 = ids[wv][i + 6 + h];
    float4 v0 = f4[(size_t)j0 * 32 + li];
    float4 v1 = f4[(size_t)j1 * 32 + li];
    float4 v2 = f4[(size_t)j2 * 32 + li];
    float4 v3 = f4[(size_t)j3 * 32 + li];
    acc.x += (v0.x + v1.x) + (v2.x + v3.x);
    acc.y += (v0.y + v1.y) + (v2.y + v3.y);
    acc.z += (v0.z + v1.z) + (v2.z + v3.z);
    acc.w += (v0.w + v1.w) + (v2.w + v3.w);
  }
  for (; i + 2 <= m; i += 2) {
    int j = ids[wv][i + h];
    float4 v = f4[(size_t)j * 32 + li];
    acc.x += v.x; acc.y += v.y; acc.z += v.z; acc.w += v.w;
  }
  if (i < m && h == 0) {              // odd leftover -> half-wave load
    int j = ids[wv][i];
    float4 v = f4[(size_t)j * 32 + li];
    acc.x += v.x; acc.y += v.y; acc.z += v.z; acc.w += v.w;
  }
  acc.x += __shfl_xor(acc.x, 32, 64);
  acc.y += __shfl_xor(acc.y, 32, 64);
  acc.z += __shfl_xor(acc.z, 32, 64);
  acc.w += __shfl_xor(acc.w, 32, 64);
  if (h == 0)
    reinterpret_cast<float4*>(out)[(size_t)r * 32 + li] = acc;
}

// ---------------------------------------------------------------------------
// MFMA split-bf16 GEMM pair (unchanged; verified absmax 0.0625)
// ---------------------------------------------------------------------------
template <bool FINAL>
__global__ __launch_bounds__(256) void gemm_pair_mfma_kernel(
    const float* __restrict__ in,
    const unsigned short* __restrict__ wahi, const unsigned short* __restrict__ walo,
    const float* __restrict__ ba,
    const unsigned short* __restrict__ wbhi, const unsigned short* __restrict__ wblo,
    const float* __restrict__ bb,
    float* __restrict__ out) {
  __shared__ unsigned short Ahi[64 * CH_];  // 16 KB
  __shared__ unsigned short Alo[64 * CH_];  // 16 KB
  int tid = threadIdx.x;
  int w = tid >> 6, l = tid & 63;
  int block_row = blockIdx.x * 64;

  const float4* in4 = reinterpret_cast<const float4*>(in) + (size_t)block_row * 32;
  #pragma unroll
  for (int i = 0; i < 8; ++i) {
    int idx = tid + i * 256;
    float4 v = in4[idx];
    int row = idx >> 5;
    int byte = row * 256 + (idx & 31) * 8;
    byte ^= (row & 7) << 4;
    unsigned short h0, l0, h1, l1, h2, l2, h3, l3;
    split_bf16(v.x, h0, l0); split_bf16(v.y, h1, l1);
    split_bf16(v.z, h2, l2); split_bf16(v.w, h3, l3);
    uint2 hp, lp;
    hp.x = (unsigned)h0 | ((unsigned)h1 << 16);
    hp.y = (unsigned)h2 | ((unsigned)h3 << 16);
    lp.x = (unsigned)l0 | ((unsigned)l1 << 16);
    lp.y = (unsigned)l2 | ((unsigned)l3 << 16);
    *reinterpret_cast<uint2*>(reinterpret_cast<char*>(Ahi) + byte) = hp;
    *reinterpret_cast<uint2*>(reinterpret_cast<char*>(Alo) + byte) = lp;
  }
  __syncthreads();

  int arow = 16 * w + (l & 15);
  int kb_off = (l >> 4) * 16;
  bf16x8 a1h[4], a1l[4];
  #pragma unroll
  for (int kb = 0; kb < 4; ++kb) {
    int byte = arow * 256 + kb * 64 + kb_off;
    byte ^= (arow & 7) << 4;
    a1h[kb] = *reinterpret_cast<const bf16x8*>(reinterpret_cast<const char*>(Ahi) + byte);
    a1l[kb] = *reinterpret_cast<const bf16x8*>(reinterpret_cast<const char*>(Alo) + byte);
  }
  __syncthreads();

  int colbase = l & 15;
  int rowoff = (l >> 4) * 4;

  #pragma unroll 2
  for (int cg = 0; cg < 8; ++cg) {
    f32x4 acc1 = {0.f, 0.f, 0.f, 0.f};
    f32x4 acc2 = {0.f, 0.f, 0.f, 0.f};
    #pragma unroll
    for (int kb = 0; kb < 4; ++kb) {
      size_t slot = (size_t)(kb * 8 + cg) * 64 + l;
      bf16x8 bh = *reinterpret_cast<const bf16x8*>(wahi + slot * 8);
      bf16x8 bl = *reinterpret_cast<const bf16x8*>(walo + slot * 8);
      acc1 = __builtin_amdgcn_mfma_f32_16x16x32_bf16(a1h[kb], bh, acc1, 0, 0, 0);
      acc1 = __builtin_amdgcn_mfma_f32_16x16x32_bf16(a1h[kb], bl, acc1, 0, 0, 0);
      acc2 = __builtin_amdgcn_mfma_f32_16x16x32_bf16(a1l[kb], bh, acc2, 0, 0, 0);
    }
    int col = cg * 16 + colbase;
    float bv = ba[col];
    #pragma unroll
    for (int r = 0; r < 4; ++r) {
      float t = fmaxf(acc1[r] + acc2[r] + bv, 0.f);
      int trow = 16 * w + rowoff + r;
      int byte = (trow * 256 + col * 2) ^ ((trow & 7) << 4);
      unsigned short th, tl;
      split_bf16(t, th, tl);
      *reinterpret_cast<unsigned short*>(reinterpret_cast<char*>(Ahi) + byte) = th;
      *reinterpret_cast<unsigned short*>(reinterpret_cast<char*>(Alo) + byte) = tl;
    }
  }
  __syncthreads();

  bf16x8 a2h[4], a2l[4];
  #pragma unroll
  for (int kb = 0; kb < 4; ++kb) {
    int byte = arow * 256 + kb * 64 + kb_off;
    byte ^= (arow & 7) << 4;
    a2h[kb] = *reinterpret_cast<const bf16x8*>(reinterpret_cast<const char*>(Ahi) + byte);
    a2l[kb] = *reinterpret_cast<const bf16x8*>(reinterpret_cast<const char*>(Alo) + byte);
  }
  if (FINAL) __syncthreads();

  float* redf = reinterpret_cast<float*>(Ahi);

  #pragma unroll 2
  for (int cg = 0; cg < 8; ++cg) {
    f32x4 acc1 = {0.f, 0.f, 0.f, 0.f};
    f32x4 acc2 = {0.f, 0.f, 0.f, 0.f};
    #pragma unroll
    for (int kb = 0; kb < 4; ++kb) {
      size_t slot = (size_t)(kb * 8 + cg) * 64 + l;
      bf16x8 bh = *reinterpret_cast<const bf16x8*>(wbhi + slot * 8);
      bf16x8 bl = *reinterpret_cast<const bf16x8*>(wblo + slot * 8);
      acc1 = __builtin_amdgcn_mfma_f32_16x16x32_bf16(a2h[kb], bh, acc1, 0, 0, 0);
      acc1 = __builtin_amdgcn_mfma_f32_16x16x32_bf16(a2h[kb], bl, acc1, 0, 0, 0);
      acc2 = __builtin_amdgcn_mfma_f32_16x16x32_bf16(a2l[kb], bh, acc2, 0, 0, 0);
    }
    int col = cg * 16 + colbase;
    float bv = bb[col];
    if (!FINAL) {
      #pragma unroll
      for (int r = 0; r < 4; ++r) {
        float v = fmaxf(acc1[r] + acc2[r] + bv, 0.f);
        out[(size_t)(block_row + 16 * w + rowoff + r) * CH_ + col] = v;
      }
    } else {
      float part = 0.f;
      #pragma unroll
      for (int r = 0; r < 4; ++r)
        part += fmaxf(acc1[r] + acc2[r] + bv, 0.f);
      redf[(w * 4 + (l >> 4)) * CH_ + col] = part;
    }
  }

  if (FINAL) {
    __syncthreads();
    if (tid < CH_) {
      float tot = 0.f;
      #pragma unroll
      for (int s = 0; s < 16; ++s) tot += redf[s * CH_ + tid];
      int b = block_row / K_;
      atomicAdd(&out[b * CH_ + tid], tot * (1.0f / (float)K_));
    }
  }
}

// ---------------------------------------------------------------------------
// pooled[r] = out1[perm[r]] * topv[r]  (wave per row, float2 lanes, XCD-swz)
// ---------------------------------------------------------------------------
__global__ __launch_bounds__(256) void pool_gather_kernel(
    const float* __restrict__ out1, const int* __restrict__ perm,
    const float* __restrict__ topv, float* __restrict__ pooled) {
  int work = xcd_work<NK_ / 4>(blockIdx.x);
  int r = work * 4 + ((int)threadIdx.x >> 6);
  int lane = threadIdx.x & 63;
  int g = perm[r];
  float v = topv[r];
  float2 t = reinterpret_cast<const float2*>(out1)[(size_t)g * 64 + lane];
  t.x *= v; t.y *= v;
  reinterpret_cast<float2*>(pooled)[(size_t)r * 64 + lane] = t;
}

// ---------------------------------------------------------------------------
extern "C" void kernel_launch(void* const* d_in, const int* in_sizes, int n_in,
                              void* d_out, int out_size, void* d_ws, size_t ws_size,
                              hipStream_t stream) {
  const float* x      = (const float*)d_in[0];
  const int*   eidx   = (const int*)d_in[1];
  const int*   src    = eidx;         // row 0
  const int*   dst    = eidx + E_;    // row 1
  const float* W1 = (const float*)d_in[3];
  const float* b1 = (const float*)d_in[4];
  const float* W2 = (const float*)d_in[5];
  const float* b2 = (const float*)d_in[6];
  const float* w_pool = (const float*)d_in[7];
  const float* W3 = (const float*)d_in[8];
  const float* b3 = (const float*)d_in[9];
  const float* W4 = (const float*)d_in[10];
  const float* b4 = (const float*)d_in[11];
  float* dout = (float*)d_out;

  // ---- workspace carve ----
  char* w = (char*)d_ws;
  auto carve = [&](size_t bytes) {
    char* p = w;
    w += (bytes + 255) & ~(size_t)255;
    return p;
  };
  float*          bufA     = (float*)carve((size_t)NB_ * CH_ * 4);
  float*          bufB     = (float*)carve((size_t)NB_ * CH_ * 4);
  unsigned*       csr      = (unsigned*)carve((size_t)E_ * 4);
  int*            ph       = (int*)  carve((size_t)B_ * CPB_ * N_ * 4);  // 4 MB
  int*            offsets1 = (int*)  carve((size_t)(NB_ + 4) * 4);
  float*          scores   = (float*)carve((size_t)NB_ * 4);
  int*            perm     = (int*)  carve((size_t)NK_ * 4);
  float*          topv     = (float*)carve((size_t)NK_ * 4);
  int*            new_idx  = (int*)  carve((size_t)NB_ * 4);
  unsigned short* whiB     = (unsigned short*)carve((size_t)4 * 16384 * 2);
  unsigned short* wloB     = (unsigned short*)carve((size_t)4 * 16384 * 2);
  auto whi = [&](int m) { return whiB + (size_t)m * 16384; };
  auto wlo = [&](int m) { return wloB + (size_t)m * 16384; };

  // zero output accumulator (poisoned 0xAA before every launch)
  hipMemsetAsync(dout, 0, (size_t)B_ * CH_ * 4, stream);

  // ---- weight split + fragment pre-pass ----
  wfrag_kernel<<<32, 256, 0, stream>>>(W1, W2, W3, W4, whiB, wloB);

  // ---- pooling scores + per-graph top-K ----
  scores_kernel<<<NB_ / 4, 256, 0, stream>>>(x, w_pool, scores, NB_);
  topk_kernel<<<B_, 1024, 0, stream>>>(scores, perm, topv, new_idx);

  // ---- chunked CSR build (hist -> scan -> packed scatter) ----
  csr_hist_kernel<<<B_ * CPB_, 256, 0, stream>>>(dst, ph);
  csr_scan_kernel<<<B_, 1024, 0, stream>>>(ph, offsets1);
  csr_scatter_kernel<<<B_ * CPB_, 256, 0, stream>>>(src, dst, ph, new_idx, csr);

  // ---- conv1: aggregate + MFMA MLP pair ----
  aggregate_kernel<<<NB_ / 4, 256, 0, stream>>>(x, offsets1, csr, bufA);
  gemm_pair_mfma_kernel<false><<<NB_ / 64, 256, 0, stream>>>(
      bufA, whi(0), wlo(0), b1, whi(1), wlo(1), b2, bufB);

  // ---- top-k gather + gate (bufB -> bufA) ----
  pool_gather_kernel<<<NK_ / 4, 256, 0, stream>>>(bufB, perm, topv, bufA);

  // ---- conv2 aggregate: compact-then-gather ----
  aggregate2_kernel<<<NK_ / 4, 256, 0, stream>>>(bufA, perm, offsets1, csr, bufB);

  // ---- conv2 MFMA MLP pair + fused global mean pool ----
  gemm_pair_mfma_kernel<true><<<NK_ / 64, 256, 0, stream>>>(
      bufB, whi(2), wlo(2), b3, whi(3), wlo(3), b4, dout);
}